// Round 1
// baseline (1597.487 us; speedup 1.0000x reference)
//
#include <hip/hip_runtime.h>

#define BATCH 2048
#define CH 512
#define NTOK 49
#define NHEAD 8
#define DHEAD 64

typedef __attribute__((ext_vector_type(8))) short bf16x8;
typedef __attribute__((ext_vector_type(4))) float f32x4;

__device__ __forceinline__ ushort f2bf(float f) {
  union { float f; unsigned u; } v; v.f = f;
  unsigned r = v.u + 0x7fffu + ((v.u >> 16) & 1u);
  return (ushort)(r >> 16);
}

#define MFMA16(a, b, c) __builtin_amdgcn_mfma_f32_16x16x32_bf16((a), (b), (c), 0, 0, 0)

// ---------------- Kernel 0: weight transpose->bf16 + rel-pos bias table ----------------
__global__ void prep_kernel(const float* __restrict__ w_qkv, const float* __restrict__ w_out,
                            const float* __restrict__ rel, ushort* __restrict__ wqkvT,
                            ushort* __restrict__ woutT, float* __restrict__ biasT) {
  int tid = blockIdx.x * blockDim.x + threadIdx.x;
  int stride = gridDim.x * blockDim.x;
  // wqkvT[o][c] = w_qkv[c][o], o in [0,1536), c in [0,512)
  for (int i = tid; i < 1536 * 512; i += stride) {
    int o = i >> 9, c = i & 511;
    wqkvT[i] = f2bf(w_qkv[c * 1536 + o]);
  }
  // woutT[o][c] = w_out[c][o]
  for (int i = tid; i < 512 * 512; i += stride) {
    int o = i >> 9, c = i & 511;
    woutT[i] = f2bf(w_out[c * 512 + o]);
  }
  // biasT[h][i][j] = rel[(ih-jh+6)][(iw-jw+6)][h]
  for (int i = tid; i < NHEAD * NTOK * NTOK; i += stride) {
    int h = i / (NTOK * NTOK);
    int rem = i - h * (NTOK * NTOK);
    int a = rem / NTOK;
    int bb = rem - a * NTOK;
    int dh = a / 7 - bb / 7 + 6;
    int dw = a % 7 - bb % 7 + 6;
    biasT[i] = rel[(dh * 13 + dw) * 8 + h];
  }
}

// ---------------- Kernel 1: LayerNorm over channels, x[b][c][n] -> xn bf16 [b][n][c] ----------------
__global__ __launch_bounds__(256) void ln_kernel(const float* __restrict__ x,
                                                 const float* __restrict__ gamma,
                                                 const float* __restrict__ beta,
                                                 ushort* __restrict__ xnW) {
  int b = blockIdx.x;
  int t = threadIdx.x;
  __shared__ float xs[CH * NTOK];
  __shared__ float muL[NTOK];
  __shared__ float rstdL[NTOK];
  const float* xb = x + (size_t)b * CH * NTOK;
  for (int i = t; i < CH * NTOK; i += 256) xs[i] = xb[i];  // xs[c*49+n]
  __syncthreads();
  if (t < NTOK) {
    float s = 0.f, s2 = 0.f;
    for (int c = 0; c < CH; c++) {
      float v = xs[c * NTOK + t];
      s += v;
      s2 += v * v;
    }
    float m = s * (1.0f / CH);
    float var = s2 * (1.0f / CH) - m * m;
    muL[t] = m;
    rstdL[t] = rsqrtf(var + 1e-5f);
  }
  __syncthreads();
  ushort* dst = xnW + (size_t)b * NTOK * CH;
  for (int i = t; i < NTOK * CH; i += 256) {
    int n = i >> 9, c = i & 511;
    float v = (xs[c * NTOK + n] - muL[n]) * rstdL[n] * gamma[c] + beta[c];
    dst[i] = f2bf(v);
  }
}

// ---------------- Kernel 2: per-b fused QKV GEMM + attention ----------------
__global__ __launch_bounds__(256) void attn_kernel(const ushort* __restrict__ xnW,
                                                   const ushort* __restrict__ wqkvT,
                                                   const float* __restrict__ biasT,
                                                   ushort* __restrict__ aoW) {
  int b = blockIdx.x;
  int t = threadIdx.x;
  int lane = t & 63;
  int wv = t >> 6;  // 4 waves

  __shared__ __align__(16) ushort xnL[64][520];
  __shared__ __align__(16) ushort qL[64][72];
  __shared__ __align__(16) ushort kL[64][72];
  __shared__ __align__(16) ushort vTL[64][72];
  __shared__ __align__(16) float sL[64][65];
  __shared__ __align__(16) ushort pL[64][72];

  // stage xn[b] (49x512 bf16) into LDS, zero pad rows 49..63
  {
    const ushort* src = xnW + (size_t)b * NTOK * CH;
    for (int i = t; i < 64 * 128; i += 256) {
      int n = i >> 7, c2 = i & 127;  // c2 indexes uint2 (4 ushorts)
      uint2 v;
      if (n < NTOK)
        v = ((const uint2*)(src + (size_t)n * CH))[c2];
      else {
        v.x = 0u;
        v.y = 0u;
      }
      *(uint2*)&xnL[n][c2 * 4] = v;
    }
  }
  __syncthreads();

  int arow = lane & 15;
  int kof = (lane >> 4) * 8;
  int wrow0 = (lane >> 4) * 4;
  int wcol = wv * 16 + (lane & 15);

  for (int h = 0; h < NHEAD; h++) {
    // ---- QKV GEMM: [64,512] @ [512, 64]x3 (this head's slices), wave wv owns d-cols [wv*16, wv*16+16) ----
    f32x4 aq[4], ak[4], av[4];
#pragma unroll
    for (int mt = 0; mt < 4; mt++) {
      aq[mt] = (f32x4){0.f, 0.f, 0.f, 0.f};
      ak[mt] = (f32x4){0.f, 0.f, 0.f, 0.f};
      av[mt] = (f32x4){0.f, 0.f, 0.f, 0.f};
    }
    int oq = h * 64 + wcol;
#pragma unroll 4
    for (int ks = 0; ks < 16; ks++) {
      int c = ks * 32 + kof;
      bf16x8 bq = *(const bf16x8*)(wqkvT + (size_t)oq * 512 + c);
      bf16x8 bk = *(const bf16x8*)(wqkvT + (size_t)(oq + 512) * 512 + c);
      bf16x8 bv = *(const bf16x8*)(wqkvT + (size_t)(oq + 1024) * 512 + c);
#pragma unroll
      for (int mt = 0; mt < 4; mt++) {
        bf16x8 a = *(const bf16x8*)&xnL[mt * 16 + arow][c];
        aq[mt] = MFMA16(a, bq, aq[mt]);
        ak[mt] = MFMA16(a, bk, ak[mt]);
        av[mt] = MFMA16(a, bv, av[mt]);
      }
    }
    __syncthreads();  // ensure previous head's PV readers are done with qL/kL/vTL/pL
#pragma unroll
    for (int mt = 0; mt < 4; mt++) {
#pragma unroll
      for (int r = 0; r < 4; r++) {
        int n = mt * 16 + wrow0 + r;
        qL[n][wcol] = f2bf(aq[mt][r] * 0.125f);  // pre-apply scale = 1/sqrt(64)
        kL[n][wcol] = f2bf(ak[mt][r]);
        vTL[wcol][n] = f2bf(av[mt][r]);  // store V transposed: vT[d][m]
      }
    }
    __syncthreads();

    // ---- S = Qs @ K^T   (64x64, K=64), wave wv owns m-cols [wv*16, ...) ----
    f32x4 as[4];
#pragma unroll
    for (int mt = 0; mt < 4; mt++) as[mt] = (f32x4){0.f, 0.f, 0.f, 0.f};
#pragma unroll
    for (int ks = 0; ks < 2; ks++) {
      int c = ks * 32 + kof;
      bf16x8 bk2 = *(const bf16x8*)&kL[wv * 16 + arow][c];
#pragma unroll
      for (int mt = 0; mt < 4; mt++) {
        bf16x8 a = *(const bf16x8*)&qL[mt * 16 + arow][c];
        as[mt] = MFMA16(a, bk2, as[mt]);
      }
    }
    const float* bh = biasT + h * NTOK * NTOK;
#pragma unroll
    for (int mt = 0; mt < 4; mt++) {
#pragma unroll
      for (int r = 0; r < 4; r++) {
        int n = mt * 16 + wrow0 + r;
        int m = wcol;
        float sv;
        if (n < NTOK && m < NTOK)
          sv = as[mt][r] + bh[n * NTOK + m];
        else
          sv = -1e30f;
        sL[n][m] = sv;
      }
    }
    __syncthreads();

    // ---- softmax per row (rows 0..48 real; rows 49..63 zero-filled) ----
    if (t < 64) {
      if (t < NTOK) {
        float mx = -3e38f;
        for (int m = 0; m < NTOK; m++) mx = fmaxf(mx, sL[t][m]);
        float sum = 0.f;
        for (int m = 0; m < NTOK; m++) sum += __expf(sL[t][m] - mx);
        float rinv = 1.f / sum;
        for (int m = 0; m < 64; m++)
          pL[t][m] = (m < NTOK) ? f2bf(__expf(sL[t][m] - mx) * rinv) : (ushort)0;
      } else {
        for (int m = 0; m < 64; m++) pL[t][m] = 0;
      }
    }
    __syncthreads();

    // ---- O = P @ V   (64x64, K=64 over m), wave wv owns d-cols ----
    f32x4 ao[4];
#pragma unroll
    for (int mt = 0; mt < 4; mt++) ao[mt] = (f32x4){0.f, 0.f, 0.f, 0.f};
#pragma unroll
    for (int ks = 0; ks < 2; ks++) {
      int c = ks * 32 + kof;
      bf16x8 bv2 = *(const bf16x8*)&vTL[wv * 16 + arow][c];
#pragma unroll
      for (int mt = 0; mt < 4; mt++) {
        bf16x8 a = *(const bf16x8*)&pL[mt * 16 + arow][c];
        ao[mt] = MFMA16(a, bv2, ao[mt]);
      }
    }
    ushort* dst = aoW + (size_t)b * NTOK * CH + h * 64;
#pragma unroll
    for (int mt = 0; mt < 4; mt++) {
#pragma unroll
      for (int r = 0; r < 4; r++) {
        int n = mt * 16 + wrow0 + r;
        if (n < NTOK) dst[(size_t)n * CH + wcol] = f2bf(ao[mt][r]);
      }
    }
    // next iteration's qL/kL/vTL writes are behind a __syncthreads(), so no barrier needed here
  }
}

// ---------------- Kernel 3: out-proj GEMM + bias + residual + transpose to [B,C,7,7] ----------------
__global__ __launch_bounds__(256) void proj_kernel(const ushort* __restrict__ aoW,
                                                   const ushort* __restrict__ woutT,
                                                   const float* __restrict__ b_out,
                                                   const float* __restrict__ x,
                                                   float* __restrict__ out) {
  int b = blockIdx.x;
  int t = threadIdx.x;
  int lane = t & 63;
  int wv = t >> 6;

  __shared__ __align__(16) ushort aL[64][520];
  __shared__ float oL[NTOK][129];

  {
    const ushort* src = aoW + (size_t)b * NTOK * CH;
    for (int i = t; i < 64 * 128; i += 256) {
      int n = i >> 7, c2 = i & 127;
      uint2 v;
      if (n < NTOK)
        v = ((const uint2*)(src + (size_t)n * CH))[c2];
      else {
        v.x = 0u;
        v.y = 0u;
      }
      *(uint2*)&aL[n][c2 * 4] = v;
    }
  }
  __syncthreads();

  int arow = lane & 15;
  int kof = (lane >> 4) * 8;
  int wrow0 = (lane >> 4) * 4;
  const float* xb = x + (size_t)b * CH * NTOK;

  for (int cc = 0; cc < 4; cc++) {
    int c0 = cc * 128;
    f32x4 acc[4][2];
#pragma unroll
    for (int mt = 0; mt < 4; mt++) {
      acc[mt][0] = (f32x4){0.f, 0.f, 0.f, 0.f};
      acc[mt][1] = (f32x4){0.f, 0.f, 0.f, 0.f};
    }
#pragma unroll 4
    for (int ks = 0; ks < 16; ks++) {
      int c = ks * 32 + kof;
      bf16x8 b0 = *(const bf16x8*)(woutT + (size_t)(c0 + (wv * 2 + 0) * 16 + arow) * 512 + c);
      bf16x8 b1 = *(const bf16x8*)(woutT + (size_t)(c0 + (wv * 2 + 1) * 16 + arow) * 512 + c);
#pragma unroll
      for (int mt = 0; mt < 4; mt++) {
        bf16x8 a = *(const bf16x8*)&aL[mt * 16 + arow][c];
        acc[mt][0] = MFMA16(a, b0, acc[mt][0]);
        acc[mt][1] = MFMA16(a, b1, acc[mt][1]);
      }
    }
#pragma unroll
    for (int mt = 0; mt < 4; mt++) {
#pragma unroll
      for (int j = 0; j < 2; j++) {
#pragma unroll
        for (int r = 0; r < 4; r++) {
          int n = mt * 16 + wrow0 + r;
          if (n < NTOK) oL[n][(wv * 2 + j) * 16 + (lane & 15)] = acc[mt][j][r];
        }
      }
    }
    __syncthreads();
    for (int i = t; i < 128 * NTOK; i += 256) {
      int cl = i / NTOK;
      int n = i - cl * NTOK;
      int c = c0 + cl;
      size_t g = ((size_t)b * CH + c) * NTOK + n;
      out[g] = oL[n][cl] + b_out[c] + xb[(size_t)c * NTOK + n];
    }
    __syncthreads();
  }
}

extern "C" void kernel_launch(void* const* d_in, const int* in_sizes, int n_in,
                              void* d_out, int out_size, void* d_ws, size_t ws_size,
                              hipStream_t stream) {
  const float* x = (const float*)d_in[0];
  const float* gamma = (const float*)d_in[1];
  const float* beta = (const float*)d_in[2];
  const float* w_qkv = (const float*)d_in[3];
  const float* rel = (const float*)d_in[4];
  const float* w_out = (const float*)d_in[5];
  const float* b_out = (const float*)d_in[6];
  float* out = (float*)d_out;

  char* ws = (char*)d_ws;
  size_t off = 0;
  ushort* wqkvT = (ushort*)(ws + off); off += (size_t)1536 * 512 * 2;       // 1.5 MB
  ushort* woutT = (ushort*)(ws + off); off += (size_t)512 * 512 * 2;        // 0.5 MB
  float* biasT = (float*)(ws + off);   off += (size_t)NHEAD * NTOK * NTOK * 4;  // 77 KB
  ushort* xnW = (ushort*)(ws + off);   off += (size_t)BATCH * NTOK * CH * 2;    // 103 MB
  ushort* aoW = (ushort*)(ws + off);   off += (size_t)BATCH * NTOK * CH * 2;    // 103 MB
  (void)ws_size;

  prep_kernel<<<512, 256, 0, stream>>>(w_qkv, w_out, rel, wqkvT, woutT, biasT);
  ln_kernel<<<BATCH, 256, 0, stream>>>(x, gamma, beta, xnW);
  attn_kernel<<<BATCH, 256, 0, stream>>>(xnW, wqkvT, biasT, aoW);
  proj_kernel<<<BATCH, 256, 0, stream>>>(aoW, woutT, b_out, x, out);
}

// Round 2
// 1375.315 us; speedup vs baseline: 1.1615x; 1.1615x over previous
//
#include <hip/hip_runtime.h>

#define BATCH 2048
#define CH 512
#define NTOK 49
#define NHEAD 8
#define DHEAD 64

typedef __attribute__((ext_vector_type(8))) short bf16x8;
typedef __attribute__((ext_vector_type(4))) float f32x4;

__device__ __forceinline__ ushort f2bf(float f) {
  union { float f; unsigned u; } v; v.f = f;
  unsigned r = v.u + 0x7fffu + ((v.u >> 16) & 1u);
  return (ushort)(r >> 16);
}

#define MFMA16(a, b, c) __builtin_amdgcn_mfma_f32_16x16x32_bf16((a), (b), (c), 0, 0, 0)

// ---------------- Kernel 0: fragment-packed bf16 weights + rel-pos bias table ----------------
// wqkvF layout: ((cb*16 + ks)*64 + lane)*8 + j  with cb 0..95 (16-col blocks of the 1536 out cols),
//   o = cb*16 + (lane&15), c = ks*32 + (lane>>4)*8 + j   -> a wave reads 1KB contiguous per B-frag.
__global__ void prep_kernel(const float* __restrict__ w_qkv, const float* __restrict__ w_out,
                            const float* __restrict__ rel, ushort* __restrict__ wqkvF,
                            ushort* __restrict__ woutF, float* __restrict__ biasT) {
  int tid = blockIdx.x * blockDim.x + threadIdx.x;
  int stride = gridDim.x * blockDim.x;
  for (int i = tid; i < 96 * 16 * 64 * 8; i += stride) {
    int j = i & 7, lane = (i >> 3) & 63, ks = (i >> 9) & 15, cb = i >> 13;
    int o = cb * 16 + (lane & 15);
    int c = ks * 32 + (lane >> 4) * 8 + j;
    wqkvF[i] = f2bf(w_qkv[c * 1536 + o]);
  }
  for (int i = tid; i < 32 * 16 * 64 * 8; i += stride) {
    int j = i & 7, lane = (i >> 3) & 63, ks = (i >> 9) & 15, cb = i >> 13;
    int o = cb * 16 + (lane & 15);
    int c = ks * 32 + (lane >> 4) * 8 + j;
    woutF[i] = f2bf(w_out[c * 512 + o]);
  }
  for (int i = tid; i < NHEAD * NTOK * NTOK; i += stride) {
    int h = i / (NTOK * NTOK);
    int rem = i - h * (NTOK * NTOK);
    int a = rem / NTOK;
    int bb = rem - a * NTOK;
    int dh = a / 7 - bb / 7 + 6;
    int dw = a % 7 - bb % 7 + 6;
    biasT[i] = rel[(dh * 13 + dw) * 8 + h];
  }
}

// ---------------- Kernel 1: LayerNorm over channels, x[b][c][n] -> xn bf16 [b][n][c] ----------------
// Chunked transpose through 25.6KB LDS (6 blocks/CU). Two passes; 2nd read is L2-hot.
__global__ __launch_bounds__(256) void ln_kernel(const float* __restrict__ x,
                                                 const float* __restrict__ gamma,
                                                 const float* __restrict__ beta,
                                                 ushort* __restrict__ xnW) {
  int b = blockIdx.x;
  int t = threadIdx.x;
  __shared__ float xs[128][51];
  __shared__ float muL[64], rsL[64];
  const float* xb = x + (size_t)b * CH * NTOK;
  int row = t >> 2, sub = t & 3;
  float s = 0.f, s2 = 0.f;
  for (int cc = 0; cc < 4; cc++) {
    const float* src = xb + cc * 128 * NTOK;
    for (int i = t; i < 128 * NTOK; i += 256) {
      int c = i / NTOK, n = i - c * NTOK;
      xs[c][n] = src[i];
    }
    __syncthreads();
    if (row < NTOK) {
      for (int c = sub; c < 128; c += 4) {
        float v = xs[c][row];
        s += v;
        s2 += v * v;
      }
    }
    __syncthreads();
  }
  s += __shfl_xor(s, 1);
  s += __shfl_xor(s, 2);
  s2 += __shfl_xor(s2, 1);
  s2 += __shfl_xor(s2, 2);
  if (sub == 0 && row < NTOK) {
    float m = s * (1.f / CH);
    muL[row] = m;
    rsL[row] = rsqrtf(s2 * (1.f / CH) - m * m + 1e-5f);
  }
  __syncthreads();
  ushort* dst = xnW + (size_t)b * NTOK * CH;
  for (int cc = 0; cc < 4; cc++) {
    const float* src = xb + cc * 128 * NTOK;
    for (int i = t; i < 128 * NTOK; i += 256) {
      int c = i / NTOK, n = i - c * NTOK;
      xs[c][n] = src[i];
    }
    __syncthreads();
    for (int i = t; i < NTOK * 128; i += 256) {
      int n = i >> 7, c = i & 127;
      float v = (xs[c][n] - muL[n]) * rsL[n] * gamma[cc * 128 + c] + beta[cc * 128 + c];
      dst[n * CH + cc * 128 + c] = f2bf(v);
    }
    __syncthreads();
  }
}

// ---------------- Kernel 2: per-b fused QKV GEMM + attention (43.5KB LDS -> 3 blocks/CU) ----------------
__global__ __launch_bounds__(256) void attn_kernel(const ushort* __restrict__ xnW,
                                                   const ushort* __restrict__ wqkvF,
                                                   const float* __restrict__ biasT,
                                                   ushort* __restrict__ aoW) {
  int b = blockIdx.x;
  int t = threadIdx.x;
  int lane = t & 63;
  int wv = t >> 6;  // 4 waves

  __shared__ __align__(16) ushort qpL[64][72];  // Q, then reused for P
  __shared__ __align__(16) ushort kL[64][72];
  __shared__ __align__(16) ushort vTL[64][72];
  __shared__ __align__(16) float sL[64][66];

  int arow = lane & 15;
  int kof = (lane >> 4) * 8;
  int wrow0 = (lane >> 4) * 4;
  int wcol = wv * 16 + arow;
  const ushort* xb = xnW + (size_t)b * NTOK * CH;
  const bf16x8 zero8 = (bf16x8){0, 0, 0, 0, 0, 0, 0, 0};

  for (int h = 0; h < NHEAD; h++) {
    // ---- QKV GEMM: A from global (L2-resident), B from frag-packed weights ----
    f32x4 aq[4], ak[4], av[4];
#pragma unroll
    for (int mt = 0; mt < 4; mt++) {
      aq[mt] = (f32x4){0.f, 0.f, 0.f, 0.f};
      ak[mt] = (f32x4){0.f, 0.f, 0.f, 0.f};
      av[mt] = (f32x4){0.f, 0.f, 0.f, 0.f};
    }
    int cbq = h * 4 + wv;
#pragma unroll 4
    for (int ks = 0; ks < 16; ks++) {
      bf16x8 bq = *(const bf16x8*)(wqkvF + ((size_t)((cbq + 0) * 16 + ks) * 64 + lane) * 8);
      bf16x8 bk = *(const bf16x8*)(wqkvF + ((size_t)((cbq + 32) * 16 + ks) * 64 + lane) * 8);
      bf16x8 bv = *(const bf16x8*)(wqkvF + ((size_t)((cbq + 64) * 16 + ks) * 64 + lane) * 8);
      int c = ks * 32 + kof;
#pragma unroll
      for (int mt = 0; mt < 4; mt++) {
        int rw = mt * 16 + arow;
        bf16x8 a;
        if (mt < 3 || rw < NTOK)
          a = *(const bf16x8*)(xb + (size_t)rw * CH + c);
        else
          a = zero8;
        aq[mt] = MFMA16(a, bq, aq[mt]);
        ak[mt] = MFMA16(a, bk, ak[mt]);
        av[mt] = MFMA16(a, bv, av[mt]);
      }
    }
    __syncthreads();  // previous head's PV readers done with qpL/vTL
#pragma unroll
    for (int mt = 0; mt < 4; mt++) {
#pragma unroll
      for (int r = 0; r < 4; r++) {
        int n = mt * 16 + wrow0 + r;
        qpL[n][wcol] = f2bf(aq[mt][r] * 0.125f);  // scale = 1/sqrt(64)
        kL[n][wcol] = f2bf(ak[mt][r]);
        vTL[wcol][n] = f2bf(av[mt][r]);  // V transposed: vT[d][m]
      }
    }
    __syncthreads();

    // ---- S = Qs @ K^T (64x64, K=64), wave wv owns m-cols [wv*16, wv*16+16) ----
    f32x4 as[4];
#pragma unroll
    for (int mt = 0; mt < 4; mt++) as[mt] = (f32x4){0.f, 0.f, 0.f, 0.f};
#pragma unroll
    for (int ks = 0; ks < 2; ks++) {
      int c = ks * 32 + kof;
      bf16x8 bk2 = *(const bf16x8*)&kL[wv * 16 + arow][c];
#pragma unroll
      for (int mt = 0; mt < 4; mt++) {
        bf16x8 a = *(const bf16x8*)&qpL[mt * 16 + arow][c];
        as[mt] = MFMA16(a, bk2, as[mt]);
      }
    }
    const float* bh = biasT + h * NTOK * NTOK;
#pragma unroll
    for (int mt = 0; mt < 4; mt++) {
#pragma unroll
      for (int r = 0; r < 4; r++) {
        int n = mt * 16 + wrow0 + r;
        if (n < NTOK && wcol < NTOK) sL[n][wcol] = as[mt][r] + bh[n * NTOK + wcol];
      }
    }
    __syncthreads();

    // ---- wave-parallel softmax: 4 threads per row, shfl_xor width-4 reduce ----
    {
      int row = t >> 2, sub = t & 3;
      float mx = -3e38f;
      if (row < NTOK)
        for (int m = sub; m < NTOK; m += 4) mx = fmaxf(mx, sL[row][m]);
      mx = fmaxf(mx, __shfl_xor(mx, 1));
      mx = fmaxf(mx, __shfl_xor(mx, 2));
      float sum = 0.f;
      if (row < NTOK)
        for (int m = sub; m < NTOK; m += 4) sum += __expf(sL[row][m] - mx);
      sum += __shfl_xor(sum, 1);
      sum += __shfl_xor(sum, 2);
      float rinv = 1.f / sum;
      for (int m = sub; m < 64; m += 4)
        qpL[row][m] = (row < NTOK && m < NTOK) ? f2bf(__expf(sL[row][m] - mx) * rinv) : (ushort)0;
    }
    __syncthreads();

    // ---- O = P @ V (64x64, K=64 over m), wave wv owns d-cols ----
    f32x4 ao[4];
#pragma unroll
    for (int mt = 0; mt < 4; mt++) ao[mt] = (f32x4){0.f, 0.f, 0.f, 0.f};
#pragma unroll
    for (int ks = 0; ks < 2; ks++) {
      int c = ks * 32 + kof;
      bf16x8 bv2 = *(const bf16x8*)&vTL[wv * 16 + arow][c];
#pragma unroll
      for (int mt = 0; mt < 4; mt++) {
        bf16x8 a = *(const bf16x8*)&qpL[mt * 16 + arow][c];
        ao[mt] = MFMA16(a, bv2, ao[mt]);
      }
    }
    ushort* dst = aoW + (size_t)b * NTOK * CH + h * 64;
#pragma unroll
    for (int mt = 0; mt < 4; mt++) {
#pragma unroll
      for (int r = 0; r < 4; r++) {
        int n = mt * 16 + wrow0 + r;
        if (n < NTOK) dst[(size_t)n * CH + wcol] = f2bf(ao[mt][r]);
      }
    }
  }
}

// ---------------- Kernel 3: out-proj GEMM + bias + residual + transpose to [B,C,7,7] ----------------
__global__ __launch_bounds__(256) void proj_kernel(const ushort* __restrict__ aoW,
                                                   const ushort* __restrict__ woutF,
                                                   const float* __restrict__ b_out,
                                                   const float* __restrict__ x,
                                                   float* __restrict__ out) {
  int b = blockIdx.x;
  int t = threadIdx.x;
  int lane = t & 63;
  int wv = t >> 6;

  __shared__ float oL[NTOK][129];

  int arow = lane & 15;
  int kof = (lane >> 4) * 8;
  int wrow0 = (lane >> 4) * 4;
  const ushort* ab = aoW + (size_t)b * NTOK * CH;
  const float* xb = x + (size_t)b * CH * NTOK;
  const bf16x8 zero8 = (bf16x8){0, 0, 0, 0, 0, 0, 0, 0};

  for (int cc = 0; cc < 4; cc++) {
    f32x4 acc[4][2];
#pragma unroll
    for (int mt = 0; mt < 4; mt++) {
      acc[mt][0] = (f32x4){0.f, 0.f, 0.f, 0.f};
      acc[mt][1] = (f32x4){0.f, 0.f, 0.f, 0.f};
    }
#pragma unroll 4
    for (int ks = 0; ks < 16; ks++) {
      bf16x8 b0 = *(const bf16x8*)(woutF + ((size_t)((cc * 8 + wv * 2 + 0) * 16 + ks) * 64 + lane) * 8);
      bf16x8 b1 = *(const bf16x8*)(woutF + ((size_t)((cc * 8 + wv * 2 + 1) * 16 + ks) * 64 + lane) * 8);
      int c = ks * 32 + kof;
#pragma unroll
      for (int mt = 0; mt < 4; mt++) {
        int rw = mt * 16 + arow;
        bf16x8 a;
        if (mt < 3 || rw < NTOK)
          a = *(const bf16x8*)(ab + (size_t)rw * CH + c);
        else
          a = zero8;
        acc[mt][0] = MFMA16(a, b0, acc[mt][0]);
        acc[mt][1] = MFMA16(a, b1, acc[mt][1]);
      }
    }
#pragma unroll
    for (int mt = 0; mt < 4; mt++) {
#pragma unroll
      for (int j = 0; j < 2; j++) {
#pragma unroll
        for (int r = 0; r < 4; r++) {
          int n = mt * 16 + wrow0 + r;
          if (n < NTOK) oL[n][(wv * 2 + j) * 16 + arow] = acc[mt][j][r];
        }
      }
    }
    __syncthreads();
    for (int i = t; i < 128 * NTOK; i += 256) {
      int cl = i / NTOK;
      int n = i - cl * NTOK;
      int c = cc * 128 + cl;
      size_t g = ((size_t)b * CH + c) * NTOK + n;
      out[g] = oL[n][cl] + b_out[c] + xb[(size_t)c * NTOK + n];
    }
    __syncthreads();
  }
}

extern "C" void kernel_launch(void* const* d_in, const int* in_sizes, int n_in,
                              void* d_out, int out_size, void* d_ws, size_t ws_size,
                              hipStream_t stream) {
  const float* x = (const float*)d_in[0];
  const float* gamma = (const float*)d_in[1];
  const float* beta = (const float*)d_in[2];
  const float* w_qkv = (const float*)d_in[3];
  const float* rel = (const float*)d_in[4];
  const float* w_out = (const float*)d_in[5];
  const float* b_out = (const float*)d_in[6];
  float* out = (float*)d_out;

  char* ws = (char*)d_ws;
  size_t off = 0;
  ushort* wqkvF = (ushort*)(ws + off); off += (size_t)1536 * 512 * 2;           // 1.5 MB
  ushort* woutF = (ushort*)(ws + off); off += (size_t)512 * 512 * 2;            // 0.5 MB
  float* biasT = (float*)(ws + off);   off += (size_t)NHEAD * NTOK * NTOK * 4;  // 77 KB
  ushort* xnW = (ushort*)(ws + off);   off += (size_t)BATCH * NTOK * CH * 2;    // 103 MB
  ushort* aoW = (ushort*)(ws + off);   off += (size_t)BATCH * NTOK * CH * 2;    // 103 MB
  (void)ws_size;

  prep_kernel<<<512, 256, 0, stream>>>(w_qkv, w_out, rel, wqkvF, woutF, biasT);
  ln_kernel<<<BATCH, 256, 0, stream>>>(x, gamma, beta, xnW);
  attn_kernel<<<BATCH, 256, 0, stream>>>(xnW, wqkvF, biasT, aoW);
  proj_kernel<<<BATCH, 256, 0, stream>>>(aoW, woutF, b_out, x, out);
}

// Round 3
// 809.705 us; speedup vs baseline: 1.9729x; 1.6985x over previous
//
#include <hip/hip_runtime.h>

#define BATCH 2048
#define CH 512
#define NTOK 49
#define NHEAD 8
#define DHEAD 64

typedef __attribute__((ext_vector_type(8))) short bf16x8;
typedef __attribute__((ext_vector_type(4))) float f32x4;

__device__ __forceinline__ ushort f2bf(float f) {
  union { float f; unsigned u; } v; v.f = f;
  unsigned r = v.u + 0x7fffu + ((v.u >> 16) & 1u);
  return (ushort)(r >> 16);
}

#define MFMA16(a, b, c) __builtin_amdgcn_mfma_f32_16x16x32_bf16((a), (b), (c), 0, 0, 0)

#define GLOAD_LDS16(gsrc, ldst)                                                  \
  __builtin_amdgcn_global_load_lds((const __attribute__((address_space(1))) void*)(gsrc), \
                                   (__attribute__((address_space(3))) void*)(ldst), 16, 0, 0)

// ---------------- Kernel 0: packed weights + padded bias table ----------------
// wqkvB[nb][kk][cbs][lane][8]: B-tile for GEMM N-block nb, K-step kk (8KB contiguous)
//   o = nb*128 + cbs*16 + (lane&15); c = kk*32 + (lane>>4)*8 + j
// woutF[cb][ks][lane][8] (proj): o = cb*16+(lane&15); c = ks*32+(lane>>4)*8+j
// biasP[h][64][64] f32: (n<49 && m<49) ? swin_bias : -1e30
__global__ void prep_kernel(const float* __restrict__ w_qkv, const float* __restrict__ w_out,
                            const float* __restrict__ rel, ushort* __restrict__ wqkvB,
                            ushort* __restrict__ woutF, float* __restrict__ biasP) {
  int tid = blockIdx.x * blockDim.x + threadIdx.x;
  int stride = gridDim.x * blockDim.x;
  for (int i = tid; i < 12 * 16 * 8 * 64 * 8; i += stride) {
    int j = i & 7, lane = (i >> 3) & 63, cbs = (i >> 9) & 7, kk = (i >> 12) & 15, nb = i >> 16;
    int o = nb * 128 + cbs * 16 + (lane & 15);
    int c = kk * 32 + (lane >> 4) * 8 + j;
    wqkvB[i] = f2bf(w_qkv[c * 1536 + o]);
  }
  for (int i = tid; i < 32 * 16 * 64 * 8; i += stride) {
    int j = i & 7, lane = (i >> 3) & 63, ks = (i >> 9) & 15, cb = i >> 13;
    int o = cb * 16 + (lane & 15);
    int c = ks * 32 + (lane >> 4) * 8 + j;
    woutF[i] = f2bf(w_out[c * 512 + o]);
  }
  for (int i = tid; i < NHEAD * 64 * 64; i += stride) {
    int h = i >> 12, n = (i >> 6) & 63, m = i & 63;
    float v = -1e30f;
    if (n < NTOK && m < NTOK) {
      int dh = n / 7 - m / 7 + 6;
      int dw = n % 7 - m % 7 + 6;
      v = rel[(dh * 13 + dw) * 8 + h];
    }
    biasP[i] = v;
  }
}

// ---------------- Kernel 1: LayerNorm over channels, x[b][c][n] -> xn bf16 [b][n][c] ----------------
__global__ __launch_bounds__(256) void ln_kernel(const float* __restrict__ x,
                                                 const float* __restrict__ gamma,
                                                 const float* __restrict__ beta,
                                                 ushort* __restrict__ xnW) {
  int b = blockIdx.x;
  int t = threadIdx.x;
  __shared__ float xs[128][51];
  __shared__ float muL[64], rsL[64];
  const float* xb = x + (size_t)b * CH * NTOK;
  int row = t >> 2, sub = t & 3;
  float s = 0.f, s2 = 0.f;
  for (int cc = 0; cc < 4; cc++) {
    const float* src = xb + cc * 128 * NTOK;
    for (int i = t; i < 128 * NTOK; i += 256) {
      int c = i / NTOK, n = i - c * NTOK;
      xs[c][n] = src[i];
    }
    __syncthreads();
    if (row < NTOK) {
      for (int c = sub; c < 128; c += 4) {
        float v = xs[c][row];
        s += v;
        s2 += v * v;
      }
    }
    __syncthreads();
  }
  s += __shfl_xor(s, 1);
  s += __shfl_xor(s, 2);
  s2 += __shfl_xor(s2, 1);
  s2 += __shfl_xor(s2, 2);
  if (sub == 0 && row < NTOK) {
    float m = s * (1.f / CH);
    muL[row] = m;
    rsL[row] = rsqrtf(s2 * (1.f / CH) - m * m + 1e-5f);
  }
  __syncthreads();
  ushort* dst = xnW + (size_t)b * NTOK * CH;
  for (int cc = 0; cc < 4; cc++) {
    const float* src = xb + cc * 128 * NTOK;
    for (int i = t; i < 128 * NTOK; i += 256) {
      int c = i / NTOK, n = i - c * NTOK;
      xs[c][n] = src[i];
    }
    __syncthreads();
    for (int i = t; i < NTOK * 128; i += 256) {
      int n = i >> 7, c = i & 127;
      float v = (xs[c][n] - muL[n]) * rsL[n] * gamma[cc * 128 + c] + beta[cc * 128 + c];
      dst[n * CH + cc * 128 + c] = f2bf(v);
    }
    __syncthreads();
  }
}

// ---------------- Kernel 2: QKV GEMM, [64x512] @ [512x128] per block ----------------
// grid 2048*12; XCD-aware: xcd = bid%8 handles b%8==xcd -> A-panel read once per XCD.
// Output: q,k -> [b][h][n<49][64] (unpadded rows + tail), v -> [b][h][d][64] (n-padded, zeros).
__global__ __launch_bounds__(256, 4) void qkv_gemm(const ushort* __restrict__ xnW,
                                                   const ushort* __restrict__ wqkvB,
                                                   ushort* __restrict__ qW,
                                                   ushort* __restrict__ kW,
                                                   ushort* __restrict__ vW) {
  int bid = blockIdx.x;
  int xcd = bid & 7, slot = bid >> 3;
  int b = xcd + 8 * (slot / 12);
  int nb = slot % 12;
  int t = threadIdx.x, lane = t & 63, w = t >> 6;

  // LDS: per buffer: A [64][32] (2048 us) + B [8][64][8] (4096 us) = 6144 ushorts (12KB); x2
  __shared__ ushort lds[12288];

  // zero A pad rows (49..63) in both buffers
  for (int i = t; i < 2 * 15 * 32; i += 256) {
    int buf = i >= 15 * 32;
    int r = i - buf * 15 * 32;
    lds[buf * 6144 + (49 + (r >> 5)) * 32 + (r & 31)] = 0;
  }

  const ushort* xb = xnW + (size_t)b * NTOK * CH;
  const ushort* wB = wqkvB + (size_t)nb * 16 * 4096;

  int srowA = w * 16 + (lane >> 2);  // staging row for A
  int scolA = (lane & 3) * 8;

  // ---- stage step 0 ----
  {
    if (srowA < NTOK) GLOAD_LDS16(xb + (size_t)srowA * CH + 0 * 32 + scolA, lds + w * 512);
    GLOAD_LDS16(wB + 0 * 4096 + (w * 2 + 0) * 512 + lane * 8, lds + 2048 + (w * 2 + 0) * 512);
    GLOAD_LDS16(wB + 0 * 4096 + (w * 2 + 1) * 512 + lane * 8, lds + 2048 + (w * 2 + 1) * 512);
  }
  __syncthreads();

  f32x4 acc[2][4];
#pragma unroll
  for (int mt = 0; mt < 2; mt++)
#pragma unroll
    for (int nt = 0; nt < 4; nt++) acc[mt][nt] = (f32x4){0.f, 0.f, 0.f, 0.f};

  int cur = 0;
  for (int step = 0; step < 16; ++step) {
    // prefetch next K-step into other buffer
    if (step < 15) {
      int nxt = cur ^ 1;
      int kk = step + 1;
      if (srowA < NTOK) GLOAD_LDS16(xb + (size_t)srowA * CH + kk * 32 + scolA, lds + nxt * 6144 + w * 512);
      GLOAD_LDS16(wB + kk * 4096 + (w * 2 + 0) * 512 + lane * 8, lds + nxt * 6144 + 2048 + (w * 2 + 0) * 512);
      GLOAD_LDS16(wB + kk * 4096 + (w * 2 + 1) * 512 + lane * 8, lds + nxt * 6144 + 2048 + (w * 2 + 1) * 512);
    }
    // compute current
    const ushort* lA = lds + cur * 6144;
    const ushort* lB = lds + cur * 6144 + 2048;
    bf16x8 bfr[4];
#pragma unroll
    for (int nt = 0; nt < 4; nt++)
      bfr[nt] = *(const bf16x8*)&lB[(((w & 1) * 4 + nt) * 64 + lane) * 8];
#pragma unroll
    for (int mt = 0; mt < 2; mt++) {
      bf16x8 afr = *(const bf16x8*)&lA[((w >> 1) * 32 + mt * 16 + (lane & 15)) * 32 + (lane >> 4) * 8];
#pragma unroll
      for (int nt = 0; nt < 4; nt++) acc[mt][nt] = MFMA16(afr, bfr[nt], acc[mt][nt]);
    }
    __syncthreads();  // drains vmcnt(0)+lgkmcnt(0): staged buffer ready, reads done
    cur ^= 1;
  }

  // ---- epilogue: through LDS (reuse), per 64-col head chunk ----
  ushort(*oL)[72] = (ushort(*)[72])lds;
  int sct = nb >> 2;  // 0=q 1=k 2=v
  int g = lane >> 4;
#pragma unroll
  for (int hh = 0; hh < 2; ++hh) {
    if ((w & 1) == hh) {
#pragma unroll
      for (int mt = 0; mt < 2; mt++)
#pragma unroll
        for (int nt = 0; nt < 4; nt++)
#pragma unroll
          for (int r = 0; r < 4; r++) {
            int row = (w >> 1) * 32 + mt * 16 + 4 * g + r;
            oL[row][nt * 16 + (lane & 15)] = f2bf(acc[mt][nt][r]);
          }
    }
    __syncthreads();
    int h = (nb & 3) * 2 + hh;
    if (sct < 2) {
      ushort* dst = (sct == 0 ? qW : kW) + (size_t)(b * 8 + h) * NTOK * 64;
      for (int i = t; i < NTOK * 8; i += 256) {
        int row = i >> 3, c8 = i & 7;
        *(uint4*)(dst + (size_t)row * 64 + c8 * 8) = *(const uint4*)&oL[row][c8 * 8];
      }
    } else {
      ushort* dst = vW + (size_t)(b * 8 + h) * 64 * 64;
      for (int i = t; i < 64 * 8; i += 256) {
        int d = i >> 3, n8 = i & 7;
        ushort tmp[8];
#pragma unroll
        for (int jj = 0; jj < 8; jj++) tmp[jj] = oL[n8 * 8 + jj][d];
        *(uint4*)(dst + (size_t)d * 64 + n8 * 8) = *(const uint4*)tmp;
      }
    }
    __syncthreads();
  }
}

// ---------------- Kernel 3: attention, one head per wave, zero block barriers ----------------
__global__ __launch_bounds__(512, 4) void attn2(const ushort* __restrict__ qW,
                                                const ushort* __restrict__ kW,
                                                const ushort* __restrict__ vW,
                                                const float* __restrict__ biasP,
                                                ushort* __restrict__ aoW) {
  int b = blockIdx.x;
  int t = threadIdx.x;
  int lane = t & 63;
  int h = t >> 6;

  __shared__ ushort pL[8][64][72];
  ushort(*pl)[72] = pL[h];

  const int c = lane & 15, g = lane >> 4;
  const ushort* qb = qW + (size_t)(b * 8 + h) * NTOK * 64;
  const ushort* kb = kW + (size_t)(b * 8 + h) * NTOK * 64;
  const ushort* vb = vW + (size_t)(b * 8 + h) * 64 * 64;
  const float* bp = biasP + h * 64 * 64;

  // ---- S = Q K^T ----
  f32x4 s[4][4];
#pragma unroll
  for (int mt = 0; mt < 4; mt++)
#pragma unroll
    for (int nt = 0; nt < 4; nt++) s[mt][nt] = (f32x4){0.f, 0.f, 0.f, 0.f};
#pragma unroll
  for (int ks = 0; ks < 2; ks++) {
    bf16x8 kf[4];
#pragma unroll
    for (int nt = 0; nt < 4; nt++)
      kf[nt] = *(const bf16x8*)(kb + (size_t)(nt * 16 + c) * 64 + ks * 32 + g * 8);
#pragma unroll
    for (int mt = 0; mt < 4; mt++) {
      bf16x8 qf = *(const bf16x8*)(qb + (size_t)(mt * 16 + c) * 64 + ks * 32 + g * 8);
#pragma unroll
      for (int nt = 0; nt < 4; nt++) s[mt][nt] = MFMA16(qf, kf[nt], s[mt][nt]);
    }
  }
  // scale + bias (bias already -1e30 on pads -> masking)
#pragma unroll
  for (int mt = 0; mt < 4; mt++)
#pragma unroll
    for (int nt = 0; nt < 4; nt++)
#pragma unroll
      for (int r = 0; r < 4; r++) {
        int n = mt * 16 + 4 * g + r;
        int m = nt * 16 + c;
        s[mt][nt][r] = s[mt][nt][r] * 0.125f + bp[n * 64 + m];
      }

  // ---- softmax per row, in registers ----
#pragma unroll
  for (int mt = 0; mt < 4; mt++)
#pragma unroll
    for (int r = 0; r < 4; r++) {
      float mx = fmaxf(fmaxf(s[mt][0][r], s[mt][1][r]), fmaxf(s[mt][2][r], s[mt][3][r]));
      mx = fmaxf(mx, __shfl_xor(mx, 1));
      mx = fmaxf(mx, __shfl_xor(mx, 2));
      mx = fmaxf(mx, __shfl_xor(mx, 4));
      mx = fmaxf(mx, __shfl_xor(mx, 8));
      float p0 = __expf(s[mt][0][r] - mx);
      float p1 = __expf(s[mt][1][r] - mx);
      float p2 = __expf(s[mt][2][r] - mx);
      float p3 = __expf(s[mt][3][r] - mx);
      float sum = p0 + p1 + p2 + p3;
      sum += __shfl_xor(sum, 1);
      sum += __shfl_xor(sum, 2);
      sum += __shfl_xor(sum, 4);
      sum += __shfl_xor(sum, 8);
      float rinv = 1.f / sum;
      int n = mt * 16 + 4 * g + r;
      pl[n][0 * 16 + c] = f2bf(p0 * rinv);
      pl[n][1 * 16 + c] = f2bf(p1 * rinv);
      pl[n][2 * 16 + c] = f2bf(p2 * rinv);
      pl[n][3 * 16 + c] = f2bf(p3 * rinv);
    }

  // ---- O = P V  (VT[d][m] layout, pads are zeros) ----
  f32x4 o[4][4];
#pragma unroll
  for (int mt = 0; mt < 4; mt++)
#pragma unroll
    for (int nt = 0; nt < 4; nt++) o[mt][nt] = (f32x4){0.f, 0.f, 0.f, 0.f};
#pragma unroll
  for (int ks = 0; ks < 2; ks++) {
    bf16x8 vf[4];
#pragma unroll
    for (int nt = 0; nt < 4; nt++)
      vf[nt] = *(const bf16x8*)(vb + (size_t)(nt * 16 + c) * 64 + ks * 32 + g * 8);
#pragma unroll
    for (int mt = 0; mt < 4; mt++) {
      bf16x8 pf = *(const bf16x8*)&pl[mt * 16 + c][ks * 32 + g * 8];
#pragma unroll
      for (int nt = 0; nt < 4; nt++) o[mt][nt] = MFMA16(pf, vf[nt], o[mt][nt]);
    }
  }

  // ---- O -> LDS (reuse pl) -> coalesced store to aoW[b][n][h*64+d] ----
#pragma unroll
  for (int mt = 0; mt < 4; mt++)
#pragma unroll
    for (int nt = 0; nt < 4; nt++)
#pragma unroll
      for (int r = 0; r < 4; r++) {
        int n = mt * 16 + 4 * g + r;
        pl[n][nt * 16 + c] = f2bf(o[mt][nt][r]);
      }
  ushort* ao = aoW + (size_t)b * NTOK * CH + h * 64;
  for (int i = lane; i < NTOK * 8; i += 64) {
    int row = i >> 3, c8 = i & 7;
    *(uint4*)(ao + (size_t)row * CH + c8 * 8) = *(const uint4*)&pl[row][c8 * 8];
  }
}

// ---------------- Kernel 4: out-proj GEMM + bias + residual + transpose ----------------
__global__ __launch_bounds__(256) void proj_kernel(const ushort* __restrict__ aoW,
                                                   const ushort* __restrict__ woutF,
                                                   const float* __restrict__ b_out,
                                                   const float* __restrict__ x,
                                                   float* __restrict__ out) {
  int b = blockIdx.x;
  int t = threadIdx.x;
  int lane = t & 63;
  int wv = t >> 6;

  __shared__ float oL[NTOK][129];

  int arow = lane & 15;
  int kof = (lane >> 4) * 8;
  int wrow0 = (lane >> 4) * 4;
  const ushort* ab = aoW + (size_t)b * NTOK * CH;
  const float* xb = x + (size_t)b * CH * NTOK;
  const bf16x8 zero8 = (bf16x8){0, 0, 0, 0, 0, 0, 0, 0};

  for (int cc = 0; cc < 4; cc++) {
    f32x4 acc[4][2];
#pragma unroll
    for (int mt = 0; mt < 4; mt++) {
      acc[mt][0] = (f32x4){0.f, 0.f, 0.f, 0.f};
      acc[mt][1] = (f32x4){0.f, 0.f, 0.f, 0.f};
    }
#pragma unroll 4
    for (int ks = 0; ks < 16; ks++) {
      bf16x8 b0 = *(const bf16x8*)(woutF + ((size_t)((cc * 8 + wv * 2 + 0) * 16 + ks) * 64 + lane) * 8);
      bf16x8 b1 = *(const bf16x8*)(woutF + ((size_t)((cc * 8 + wv * 2 + 1) * 16 + ks) * 64 + lane) * 8);
      int c = ks * 32 + kof;
#pragma unroll
      for (int mt = 0; mt < 4; mt++) {
        int rw = mt * 16 + arow;
        bf16x8 a;
        if (mt < 3 || rw < NTOK)
          a = *(const bf16x8*)(ab + (size_t)rw * CH + c);
        else
          a = zero8;
        acc[mt][0] = MFMA16(a, b0, acc[mt][0]);
        acc[mt][1] = MFMA16(a, b1, acc[mt][1]);
      }
    }
#pragma unroll
    for (int mt = 0; mt < 4; mt++) {
#pragma unroll
      for (int j = 0; j < 2; j++) {
#pragma unroll
        for (int r = 0; r < 4; r++) {
          int n = mt * 16 + wrow0 + r;
          if (n < NTOK) oL[n][(wv * 2 + j) * 16 + arow] = acc[mt][j][r];
        }
      }
    }
    __syncthreads();
    for (int i = t; i < 128 * NTOK; i += 256) {
      int cl = i / NTOK;
      int n = i - cl * NTOK;
      int c = cc * 128 + cl;
      size_t gdx = ((size_t)b * CH + c) * NTOK + n;
      out[gdx] = oL[n][cl] + b_out[c] + xb[(size_t)c * NTOK + n];
    }
    __syncthreads();
  }
}

extern "C" void kernel_launch(void* const* d_in, const int* in_sizes, int n_in,
                              void* d_out, int out_size, void* d_ws, size_t ws_size,
                              hipStream_t stream) {
  const float* x = (const float*)d_in[0];
  const float* gamma = (const float*)d_in[1];
  const float* beta = (const float*)d_in[2];
  const float* w_qkv = (const float*)d_in[3];
  const float* rel = (const float*)d_in[4];
  const float* w_out = (const float*)d_in[5];
  const float* b_out = (const float*)d_in[6];
  float* out = (float*)d_out;

  char* ws = (char*)d_ws;
  size_t off = 0;
  ushort* wqkvB = (ushort*)(ws + off); off += (size_t)12 * 16 * 4096 * 2;            // 1.5 MB
  ushort* woutF = (ushort*)(ws + off); off += (size_t)512 * 512 * 2;                 // 0.5 MB
  float* biasP = (float*)(ws + off);   off += (size_t)NHEAD * 64 * 64 * 4;           // 128 KB
  ushort* qW = (ushort*)(ws + off);    off += ((size_t)BATCH * 8 * NTOK * 64 + 1024) * 2;  // ~98.6 MB (+tail)
  ushort* kW = (ushort*)(ws + off);    off += ((size_t)BATCH * 8 * NTOK * 64 + 1024) * 2;  // ~98.6 MB
  ushort* vW = (ushort*)(ws + off);    off += (size_t)BATCH * 8 * 64 * 64 * 2;       // 134 MB
  ushort* xnW = (ushort*)(ws + off);   off += (size_t)BATCH * NTOK * CH * 2;         // 103 MB (xn then ao)
  ushort* aoW = xnW;  // alias: xn dead after qkv_gemm
  (void)ws_size;

  prep_kernel<<<1024, 256, 0, stream>>>(w_qkv, w_out, rel, wqkvB, woutF, biasP);
  ln_kernel<<<BATCH, 256, 0, stream>>>(x, gamma, beta, xnW);
  qkv_gemm<<<BATCH * 12, 256, 0, stream>>>(xnW, wqkvB, qW, kW, vW);
  attn2<<<BATCH, 512, 0, stream>>>(qW, kW, vW, biasP, aoW);
  proj_kernel<<<BATCH, 256, 0, stream>>>(aoW, woutF, b_out, x, out);
}

// Round 4
// 786.829 us; speedup vs baseline: 2.0303x; 1.0291x over previous
//
#include <hip/hip_runtime.h>

#define BATCH 2048
#define CH 512
#define NTOK 49
#define NHEAD 8
#define DHEAD 64

typedef __attribute__((ext_vector_type(8))) short bf16x8;
typedef __attribute__((ext_vector_type(4))) float f32x4;

__device__ __forceinline__ ushort f2bf(float f) {
  union { float f; unsigned u; } v; v.f = f;
  unsigned r = v.u + 0x7fffu + ((v.u >> 16) & 1u);
  return (ushort)(r >> 16);
}

#define MFMA16(a, b, c) __builtin_amdgcn_mfma_f32_16x16x32_bf16((a), (b), (c), 0, 0, 0)

#define GLOAD_LDS16(gsrc, ldst)                                                  \
  __builtin_amdgcn_global_load_lds((const __attribute__((address_space(1))) void*)(gsrc), \
                                   (__attribute__((address_space(3))) void*)(ldst), 16, 0, 0)

// ---------------- Kernel 0: packed weights + padded bias table ----------------
__global__ void prep_kernel(const float* __restrict__ w_qkv, const float* __restrict__ w_out,
                            const float* __restrict__ rel, ushort* __restrict__ wqkvB,
                            ushort* __restrict__ woutF, float* __restrict__ biasP) {
  int tid = blockIdx.x * blockDim.x + threadIdx.x;
  int stride = gridDim.x * blockDim.x;
  for (int i = tid; i < 12 * 16 * 8 * 64 * 8; i += stride) {
    int j = i & 7, lane = (i >> 3) & 63, cbs = (i >> 9) & 7, kk = (i >> 12) & 15, nb = i >> 16;
    int o = nb * 128 + cbs * 16 + (lane & 15);
    int c = kk * 32 + (lane >> 4) * 8 + j;
    wqkvB[i] = f2bf(w_qkv[c * 1536 + o]);
  }
  for (int i = tid; i < 32 * 16 * 64 * 8; i += stride) {
    int j = i & 7, lane = (i >> 3) & 63, ks = (i >> 9) & 15, cb = i >> 13;
    int o = cb * 16 + (lane & 15);
    int c = ks * 32 + (lane >> 4) * 8 + j;
    woutF[i] = f2bf(w_out[c * 512 + o]);
  }
  for (int i = tid; i < NHEAD * 64 * 64; i += stride) {
    int h = i >> 12, n = (i >> 6) & 63, m = i & 63;
    float v = -1e30f;
    if (n < NTOK && m < NTOK) {
      int dh = n / 7 - m / 7 + 6;
      int dw = n % 7 - m % 7 + 6;
      v = rel[(dh * 13 + dw) * 8 + h];
    }
    biasP[i] = v;
  }
}

// ---------------- Kernel 1: LayerNorm over channels, x[b][c][n] -> xn bf16 [b][n][c] ----------------
// float4 staging loads + ushort8 output stores.
__global__ __launch_bounds__(256) void ln_kernel(const float* __restrict__ x,
                                                 const float* __restrict__ gamma,
                                                 const float* __restrict__ beta,
                                                 ushort* __restrict__ xnW) {
  int b = blockIdx.x;
  int t = threadIdx.x;
  __shared__ float xs[128][51];
  __shared__ float muL[64], rsL[64];
  const float* xb = x + (size_t)b * CH * NTOK;
  int row = t >> 2, sub = t & 3;
  float s = 0.f, s2 = 0.f;
  for (int cc = 0; cc < 4; cc++) {
    const float4* src4 = (const float4*)(xb + cc * 128 * NTOK);
    for (int i4 = t; i4 < 1568; i4 += 256) {
      float4 v = src4[i4];
      int lf = i4 * 4;
#pragma unroll
      for (int e = 0; e < 4; e++) {
        int c = (lf + e) / NTOK, n = (lf + e) - c * NTOK;
        xs[c][n] = ((const float*)&v)[e];
      }
    }
    __syncthreads();
    if (row < NTOK) {
      for (int c = sub; c < 128; c += 4) {
        float v = xs[c][row];
        s += v;
        s2 += v * v;
      }
    }
    __syncthreads();
  }
  s += __shfl_xor(s, 1);
  s += __shfl_xor(s, 2);
  s2 += __shfl_xor(s2, 1);
  s2 += __shfl_xor(s2, 2);
  if (sub == 0 && row < NTOK) {
    float m = s * (1.f / CH);
    muL[row] = m;
    rsL[row] = rsqrtf(s2 * (1.f / CH) - m * m + 1e-5f);
  }
  __syncthreads();
  ushort* dst = xnW + (size_t)b * NTOK * CH;
  for (int cc = 0; cc < 4; cc++) {
    const float4* src4 = (const float4*)(xb + cc * 128 * NTOK);
    for (int i4 = t; i4 < 1568; i4 += 256) {
      float4 v = src4[i4];
      int lf = i4 * 4;
#pragma unroll
      for (int e = 0; e < 4; e++) {
        int c = (lf + e) / NTOK, n = (lf + e) - c * NTOK;
        xs[c][n] = ((const float*)&v)[e];
      }
    }
    __syncthreads();
    // 49 rows x 16 ushort8-chunks of 128 cols
    for (int i = t; i < NTOK * 16; i += 256) {
      int n = i >> 4, c0 = (i & 15) * 8;
      ushort tmp[8];
#pragma unroll
      for (int j = 0; j < 8; j++) {
        int c = cc * 128 + c0 + j;
        tmp[j] = f2bf((xs[c0 + j][n] - muL[n]) * rsL[n] * gamma[c] + beta[c]);
      }
      *(uint4*)(dst + (size_t)n * CH + cc * 128 + c0) = *(const uint4*)tmp;
    }
    __syncthreads();
  }
}

// ---------------- Kernel 2: QKV GEMM, [64x512] @ [512x128] per block ----------------
__global__ __launch_bounds__(256, 4) void qkv_gemm(const ushort* __restrict__ xnW,
                                                   const ushort* __restrict__ wqkvB,
                                                   ushort* __restrict__ qW,
                                                   ushort* __restrict__ kW,
                                                   ushort* __restrict__ vW) {
  int bid = blockIdx.x;
  int xcd = bid & 7, slot = bid >> 3;
  int b = xcd + 8 * (slot / 12);
  int nb = slot % 12;
  int t = threadIdx.x, lane = t & 63, w = t >> 6;

  __shared__ ushort lds[12288];

  for (int i = t; i < 2 * 15 * 32; i += 256) {
    int buf = i >= 15 * 32;
    int r = i - buf * 15 * 32;
    lds[buf * 6144 + (49 + (r >> 5)) * 32 + (r & 31)] = 0;
  }

  const ushort* xb = xnW + (size_t)b * NTOK * CH;
  const ushort* wB = wqkvB + (size_t)nb * 16 * 4096;

  int srowA = w * 16 + (lane >> 2);
  int scolA = (lane & 3) * 8;

  {
    if (srowA < NTOK) GLOAD_LDS16(xb + (size_t)srowA * CH + 0 * 32 + scolA, lds + w * 512);
    GLOAD_LDS16(wB + 0 * 4096 + (w * 2 + 0) * 512 + lane * 8, lds + 2048 + (w * 2 + 0) * 512);
    GLOAD_LDS16(wB + 0 * 4096 + (w * 2 + 1) * 512 + lane * 8, lds + 2048 + (w * 2 + 1) * 512);
  }
  __syncthreads();

  f32x4 acc[2][4];
#pragma unroll
  for (int mt = 0; mt < 2; mt++)
#pragma unroll
    for (int nt = 0; nt < 4; nt++) acc[mt][nt] = (f32x4){0.f, 0.f, 0.f, 0.f};

  int cur = 0;
  for (int step = 0; step < 16; ++step) {
    if (step < 15) {
      int nxt = cur ^ 1;
      int kk = step + 1;
      if (srowA < NTOK) GLOAD_LDS16(xb + (size_t)srowA * CH + kk * 32 + scolA, lds + nxt * 6144 + w * 512);
      GLOAD_LDS16(wB + kk * 4096 + (w * 2 + 0) * 512 + lane * 8, lds + nxt * 6144 + 2048 + (w * 2 + 0) * 512);
      GLOAD_LDS16(wB + kk * 4096 + (w * 2 + 1) * 512 + lane * 8, lds + nxt * 6144 + 2048 + (w * 2 + 1) * 512);
    }
    const ushort* lA = lds + cur * 6144;
    const ushort* lB = lds + cur * 6144 + 2048;
    bf16x8 bfr[4];
#pragma unroll
    for (int nt = 0; nt < 4; nt++)
      bfr[nt] = *(const bf16x8*)&lB[(((w & 1) * 4 + nt) * 64 + lane) * 8];
#pragma unroll
    for (int mt = 0; mt < 2; mt++) {
      bf16x8 afr = *(const bf16x8*)&lA[((w >> 1) * 32 + mt * 16 + (lane & 15)) * 32 + (lane >> 4) * 8];
#pragma unroll
      for (int nt = 0; nt < 4; nt++) acc[mt][nt] = MFMA16(afr, bfr[nt], acc[mt][nt]);
    }
    __syncthreads();
    cur ^= 1;
  }

  ushort(*oL)[72] = (ushort(*)[72])lds;
  int sct = nb >> 2;
  int g = lane >> 4;
#pragma unroll
  for (int hh = 0; hh < 2; ++hh) {
    if ((w & 1) == hh) {
#pragma unroll
      for (int mt = 0; mt < 2; mt++)
#pragma unroll
        for (int nt = 0; nt < 4; nt++)
#pragma unroll
          for (int r = 0; r < 4; r++) {
            int row = (w >> 1) * 32 + mt * 16 + 4 * g + r;
            oL[row][nt * 16 + (lane & 15)] = f2bf(acc[mt][nt][r]);
          }
    }
    __syncthreads();
    int h = (nb & 3) * 2 + hh;
    if (sct < 2) {
      ushort* dst = (sct == 0 ? qW : kW) + (size_t)(b * 8 + h) * NTOK * 64;
      for (int i = t; i < NTOK * 8; i += 256) {
        int row = i >> 3, c8 = i & 7;
        *(uint4*)(dst + (size_t)row * 64 + c8 * 8) = *(const uint4*)&oL[row][c8 * 8];
      }
    } else {
      ushort* dst = vW + (size_t)(b * 8 + h) * 64 * 64;
      for (int i = t; i < 64 * 8; i += 256) {
        int d = i >> 3, n8 = i & 7;
        ushort tmp[8];
#pragma unroll
        for (int jj = 0; jj < 8; jj++) tmp[jj] = oL[n8 * 8 + jj][d];
        *(uint4*)(dst + (size_t)d * 64 + n8 * 8) = *(const uint4*)tmp;
      }
    }
    __syncthreads();
  }
}

// ---------------- Kernel 3: attention, one head per wave, zero block barriers ----------------
__global__ __launch_bounds__(512, 4) void attn2(const ushort* __restrict__ qW,
                                                const ushort* __restrict__ kW,
                                                const ushort* __restrict__ vW,
                                                const float* __restrict__ biasP,
                                                ushort* __restrict__ aoW) {
  int b = blockIdx.x;
  int t = threadIdx.x;
  int lane = t & 63;
  int h = t >> 6;

  __shared__ ushort pL[8][64][72];
  ushort(*pl)[72] = pL[h];

  const int c = lane & 15, g = lane >> 4;
  const ushort* qb = qW + (size_t)(b * 8 + h) * NTOK * 64;
  const ushort* kb = kW + (size_t)(b * 8 + h) * NTOK * 64;
  const ushort* vb = vW + (size_t)(b * 8 + h) * 64 * 64;
  const float* bp = biasP + h * 64 * 64;

  f32x4 s[4][4];
#pragma unroll
  for (int mt = 0; mt < 4; mt++)
#pragma unroll
    for (int nt = 0; nt < 4; nt++) s[mt][nt] = (f32x4){0.f, 0.f, 0.f, 0.f};
#pragma unroll
  for (int ks = 0; ks < 2; ks++) {
    bf16x8 kf[4];
#pragma unroll
    for (int nt = 0; nt < 4; nt++)
      kf[nt] = *(const bf16x8*)(kb + (size_t)(nt * 16 + c) * 64 + ks * 32 + g * 8);
#pragma unroll
    for (int mt = 0; mt < 4; mt++) {
      bf16x8 qf = *(const bf16x8*)(qb + (size_t)(mt * 16 + c) * 64 + ks * 32 + g * 8);
#pragma unroll
      for (int nt = 0; nt < 4; nt++) s[mt][nt] = MFMA16(qf, kf[nt], s[mt][nt]);
    }
  }
#pragma unroll
  for (int mt = 0; mt < 4; mt++)
#pragma unroll
    for (int nt = 0; nt < 4; nt++)
#pragma unroll
      for (int r = 0; r < 4; r++) {
        int n = mt * 16 + 4 * g + r;
        int m = nt * 16 + c;
        s[mt][nt][r] = s[mt][nt][r] * 0.125f + bp[n * 64 + m];
      }

#pragma unroll
  for (int mt = 0; mt < 4; mt++)
#pragma unroll
    for (int r = 0; r < 4; r++) {
      float mx = fmaxf(fmaxf(s[mt][0][r], s[mt][1][r]), fmaxf(s[mt][2][r], s[mt][3][r]));
      mx = fmaxf(mx, __shfl_xor(mx, 1));
      mx = fmaxf(mx, __shfl_xor(mx, 2));
      mx = fmaxf(mx, __shfl_xor(mx, 4));
      mx = fmaxf(mx, __shfl_xor(mx, 8));
      float p0 = __expf(s[mt][0][r] - mx);
      float p1 = __expf(s[mt][1][r] - mx);
      float p2 = __expf(s[mt][2][r] - mx);
      float p3 = __expf(s[mt][3][r] - mx);
      float sum = p0 + p1 + p2 + p3;
      sum += __shfl_xor(sum, 1);
      sum += __shfl_xor(sum, 2);
      sum += __shfl_xor(sum, 4);
      sum += __shfl_xor(sum, 8);
      float rinv = 1.f / sum;
      int n = mt * 16 + 4 * g + r;
      pl[n][0 * 16 + c] = f2bf(p0 * rinv);
      pl[n][1 * 16 + c] = f2bf(p1 * rinv);
      pl[n][2 * 16 + c] = f2bf(p2 * rinv);
      pl[n][3 * 16 + c] = f2bf(p3 * rinv);
    }

  f32x4 o[4][4];
#pragma unroll
  for (int mt = 0; mt < 4; mt++)
#pragma unroll
    for (int nt = 0; nt < 4; nt++) o[mt][nt] = (f32x4){0.f, 0.f, 0.f, 0.f};
#pragma unroll
  for (int ks = 0; ks < 2; ks++) {
    bf16x8 vf[4];
#pragma unroll
    for (int nt = 0; nt < 4; nt++)
      vf[nt] = *(const bf16x8*)(vb + (size_t)(nt * 16 + c) * 64 + ks * 32 + g * 8);
#pragma unroll
    for (int mt = 0; mt < 4; mt++) {
      bf16x8 pf = *(const bf16x8*)&pl[mt * 16 + c][ks * 32 + g * 8];
#pragma unroll
      for (int nt = 0; nt < 4; nt++) o[mt][nt] = MFMA16(pf, vf[nt], o[mt][nt]);
    }
  }

#pragma unroll
  for (int mt = 0; mt < 4; mt++)
#pragma unroll
    for (int nt = 0; nt < 4; nt++)
#pragma unroll
      for (int r = 0; r < 4; r++) {
        int n = mt * 16 + 4 * g + r;
        pl[n][nt * 16 + c] = f2bf(o[mt][nt][r]);
      }
  ushort* ao = aoW + (size_t)b * NTOK * CH + h * 64;
  for (int i = lane; i < NTOK * 8; i += 64) {
    int row = i >> 3, c8 = i & 7;
    *(uint4*)(ao + (size_t)row * CH + c8 * 8) = *(const uint4*)&pl[row][c8 * 8];
  }
}

// ---------------- Kernel 4: out-proj GEMM + bias + residual, vectorized ----------------
// 512 threads / 8 waves; wave w owns output cols [w*64, w*64+64). Single K-pass.
__global__ __launch_bounds__(512) void proj_kernel(const ushort* __restrict__ aoW,
                                                   const ushort* __restrict__ woutF,
                                                   const float* __restrict__ b_out,
                                                   const float* __restrict__ x,
                                                   float* __restrict__ out) {
  int b = blockIdx.x;
  int t = threadIdx.x;
  int lane = t & 63;
  int w = t >> 6;

  __shared__ float oL[128][52];

  int arow = lane & 15;
  int kof = (lane >> 4) * 8;
  int g = lane >> 4;
  const ushort* ab = aoW + (size_t)b * NTOK * CH;
  const bf16x8 zero8 = (bf16x8){0, 0, 0, 0, 0, 0, 0, 0};

  f32x4 acc[4][4];
#pragma unroll
  for (int mt = 0; mt < 4; mt++)
#pragma unroll
    for (int nt = 0; nt < 4; nt++) acc[mt][nt] = (f32x4){0.f, 0.f, 0.f, 0.f};

#pragma unroll 4
  for (int ks = 0; ks < 16; ks++) {
    bf16x8 bfr[4];
#pragma unroll
    for (int nt = 0; nt < 4; nt++)
      bfr[nt] = *(const bf16x8*)(woutF + ((size_t)((w * 4 + nt) * 16 + ks) * 64 + lane) * 8);
    int c = ks * 32 + kof;
#pragma unroll
    for (int mt = 0; mt < 4; mt++) {
      int rw = mt * 16 + arow;
      bf16x8 a;
      if (mt < 3 || rw < NTOK)
        a = *(const bf16x8*)(ab + (size_t)rw * CH + c);
      else
        a = zero8;
#pragma unroll
      for (int nt = 0; nt < 4; nt++) acc[mt][nt] = MFMA16(a, bfr[nt], acc[mt][nt]);
    }
  }

  // epilogue: 4 chunks of 128 cols; waves 2cc,2cc+1 dump col-major, all threads f4-store
  const float* xb = x + (size_t)b * CH * NTOK;
  for (int cc = 0; cc < 4; cc++) {
    if ((w >> 1) == cc) {
#pragma unroll
      for (int mt = 0; mt < 4; mt++)
#pragma unroll
        for (int nt = 0; nt < 4; nt++)
#pragma unroll
          for (int r = 0; r < 4; r++) {
            int n = mt * 16 + 4 * g + r;
            if (n < NTOK) oL[(w & 1) * 64 + nt * 16 + arow][n] = acc[mt][nt][r];
          }
    }
    __syncthreads();
    const float4* x4 = (const float4*)(xb + cc * 128 * NTOK);
    float4* o4 = (float4*)(out + ((size_t)b * CH + cc * 128) * NTOK);
    for (int i = t; i < 1568; i += 512) {
      float4 xv = x4[i];
      float4 ov;
      int lf = i * 4;
#pragma unroll
      for (int e = 0; e < 4; e++) {
        int cl = (lf + e) / NTOK, n = (lf + e) - cl * NTOK;
        ((float*)&ov)[e] = oL[cl][n] + b_out[cc * 128 + cl] + ((const float*)&xv)[e];
      }
      o4[i] = ov;
    }
    __syncthreads();
  }
}

extern "C" void kernel_launch(void* const* d_in, const int* in_sizes, int n_in,
                              void* d_out, int out_size, void* d_ws, size_t ws_size,
                              hipStream_t stream) {
  const float* x = (const float*)d_in[0];
  const float* gamma = (const float*)d_in[1];
  const float* beta = (const float*)d_in[2];
  const float* w_qkv = (const float*)d_in[3];
  const float* rel = (const float*)d_in[4];
  const float* w_out = (const float*)d_in[5];
  const float* b_out = (const float*)d_in[6];
  float* out = (float*)d_out;

  char* ws = (char*)d_ws;
  size_t off = 0;
  ushort* wqkvB = (ushort*)(ws + off); off += (size_t)12 * 16 * 4096 * 2;
  ushort* woutF = (ushort*)(ws + off); off += (size_t)512 * 512 * 2;
  float* biasP = (float*)(ws + off);   off += (size_t)NHEAD * 64 * 64 * 4;
  ushort* qW = (ushort*)(ws + off);    off += ((size_t)BATCH * 8 * NTOK * 64 + 1024) * 2;
  ushort* kW = (ushort*)(ws + off);    off += ((size_t)BATCH * 8 * NTOK * 64 + 1024) * 2;
  ushort* vW = (ushort*)(ws + off);    off += (size_t)BATCH * 8 * 64 * 64 * 2;
  ushort* xnW = (ushort*)(ws + off);   off += (size_t)BATCH * NTOK * CH * 2;
  ushort* aoW = xnW;  // alias: xn dead after qkv_gemm
  (void)ws_size;

  prep_kernel<<<1024, 256, 0, stream>>>(w_qkv, w_out, rel, wqkvB, woutF, biasP);
  ln_kernel<<<BATCH, 256, 0, stream>>>(x, gamma, beta, xnW);
  qkv_gemm<<<BATCH * 12, 256, 0, stream>>>(xnW, wqkvB, qW, kW, vW);
  attn2<<<BATCH, 512, 0, stream>>>(qW, kW, vW, biasP, aoW);
  proj_kernel<<<BATCH, 512, 0, stream>>>(aoW, woutF, b_out, x, out);
}

// Round 5
// 663.623 us; speedup vs baseline: 2.4072x; 1.1857x over previous
//
#include <hip/hip_runtime.h>

#define BATCH 2048
#define CH 512
#define NTOK 49
#define NHEAD 8
#define DHEAD 64

typedef __attribute__((ext_vector_type(8))) short bf16x8;
typedef __attribute__((ext_vector_type(4))) float f32x4;

__device__ __forceinline__ ushort f2bf(float f) {
  union { float f; unsigned u; } v; v.f = f;
  unsigned r = v.u + 0x7fffu + ((v.u >> 16) & 1u);
  return (ushort)(r >> 16);
}

#define MFMA16(a, b, c) __builtin_amdgcn_mfma_f32_16x16x32_bf16((a), (b), (c), 0, 0, 0)

#define GLOAD_LDS16(gsrc, ldst)                                                  \
  __builtin_amdgcn_global_load_lds((const __attribute__((address_space(1))) void*)(gsrc), \
                                   (__attribute__((address_space(3))) void*)(ldst), 16, 0, 0)

// ---------------- Kernel 0: packed weights + padded bias table ----------------
// wqkvB[nb][kk] = 8KB block [cbs(8)][lane(64)][8]: o = nb*128+cbs*16+(lane&15), c = kk*32+(lane>>4)*8+j
// woutF[cb][ks][lane][8]: o = cb*16+(lane&15), c = ks*32+(lane>>4)*8+j
// biasP[h][64][64] f32: (n<49 && m<49) ? swin_bias : -1e30
__global__ void prep_kernel(const float* __restrict__ w_qkv, const float* __restrict__ w_out,
                            const float* __restrict__ rel, ushort* __restrict__ wqkvB,
                            ushort* __restrict__ woutF, float* __restrict__ biasP) {
  int tid = blockIdx.x * blockDim.x + threadIdx.x;
  int stride = gridDim.x * blockDim.x;
  for (int i = tid; i < 12 * 16 * 8 * 64 * 8; i += stride) {
    int j = i & 7, lane = (i >> 3) & 63, cbs = (i >> 9) & 7, kk = (i >> 12) & 15, nb = i >> 16;
    int o = nb * 128 + cbs * 16 + (lane & 15);
    int c = kk * 32 + (lane >> 4) * 8 + j;
    wqkvB[i] = f2bf(w_qkv[c * 1536 + o]);
  }
  for (int i = tid; i < 32 * 16 * 64 * 8; i += stride) {
    int j = i & 7, lane = (i >> 3) & 63, ks = (i >> 9) & 15, cb = i >> 13;
    int o = cb * 16 + (lane & 15);
    int c = ks * 32 + (lane >> 4) * 8 + j;
    woutF[i] = f2bf(w_out[c * 512 + o]);
  }
  for (int i = tid; i < NHEAD * 64 * 64; i += stride) {
    int h = i >> 12, n = (i >> 6) & 63, m = i & 63;
    float v = -1e30f;
    if (n < NTOK && m < NTOK) {
      int dh = n / 7 - m / 7 + 6;
      int dw = n % 7 - m % 7 + 6;
      v = rel[(dh * 13 + dw) * 8 + h];
    }
    biasP[i] = v;
  }
}

// ---------------- Kernel 1: LayerNorm over channels, x[b][c][n] -> xn bf16 [b][n][c] ----------------
__global__ __launch_bounds__(256) void ln_kernel(const float* __restrict__ x,
                                                 const float* __restrict__ gamma,
                                                 const float* __restrict__ beta,
                                                 ushort* __restrict__ xnW) {
  int b = blockIdx.x;
  int t = threadIdx.x;
  __shared__ float xs[128][51];
  __shared__ float muL[64], rsL[64];
  const float* xb = x + (size_t)b * CH * NTOK;
  int row = t >> 2, sub = t & 3;
  float s = 0.f, s2 = 0.f;
  for (int cc = 0; cc < 4; cc++) {
    const float4* src4 = (const float4*)(xb + cc * 128 * NTOK);
    for (int i4 = t; i4 < 1568; i4 += 256) {
      float4 v = src4[i4];
      int lf = i4 * 4;
#pragma unroll
      for (int e = 0; e < 4; e++) {
        int c = (lf + e) / NTOK, n = (lf + e) - c * NTOK;
        xs[c][n] = ((const float*)&v)[e];
      }
    }
    __syncthreads();
    if (row < NTOK) {
      for (int c = sub; c < 128; c += 4) {
        float v = xs[c][row];
        s += v;
        s2 += v * v;
      }
    }
    __syncthreads();
  }
  s += __shfl_xor(s, 1);
  s += __shfl_xor(s, 2);
  s2 += __shfl_xor(s2, 1);
  s2 += __shfl_xor(s2, 2);
  if (sub == 0 && row < NTOK) {
    float m = s * (1.f / CH);
    muL[row] = m;
    rsL[row] = rsqrtf(s2 * (1.f / CH) - m * m + 1e-5f);
  }
  __syncthreads();
  ushort* dst = xnW + (size_t)b * NTOK * CH;
  for (int cc = 0; cc < 4; cc++) {
    const float4* src4 = (const float4*)(xb + cc * 128 * NTOK);
    for (int i4 = t; i4 < 1568; i4 += 256) {
      float4 v = src4[i4];
      int lf = i4 * 4;
#pragma unroll
      for (int e = 0; e < 4; e++) {
        int c = (lf + e) / NTOK, n = (lf + e) - c * NTOK;
        xs[c][n] = ((const float*)&v)[e];
      }
    }
    __syncthreads();
    for (int i = t; i < NTOK * 16; i += 256) {
      int n = i >> 4, c0 = (i & 15) * 8;
      ushort tmp[8];
#pragma unroll
      for (int j = 0; j < 8; j++) {
        int c = cc * 128 + c0 + j;
        tmp[j] = f2bf((xs[c0 + j][n] - muL[n]) * rsL[n] * gamma[c] + beta[c]);
      }
      *(uint4*)(dst + (size_t)n * CH + cc * 128 + c0) = *(const uint4*)tmp;
    }
    __syncthreads();
  }
}

// ---------------- Kernel 2: QKV GEMM, 128x128 tile (2 batches) x 12 col-blocks ----------------
// 4 waves, wave = 64x64 sub-tile; dbuf global_load_lds; A XOR-swizzled (chunk ^= (row>>1)&3).
__global__ __launch_bounds__(256, 4) void qkv_gemm(const ushort* __restrict__ xnW,
                                                   const ushort* __restrict__ wqkvB,
                                                   ushort* __restrict__ qW,
                                                   ushort* __restrict__ kW,
                                                   ushort* __restrict__ vW) {
  int bid = blockIdx.x;
  int f = (bid & 7) * 1536 + (bid >> 3);  // bijective XCD swizzle (12288 = 8*1536)
  int mb = f / 12, nb = f - mb * 12;
  int b0 = mb * 2;
  int t = threadIdx.x, lane = t & 63, w = t >> 6;
  int wm = w >> 1, wn = w & 1;

  // per buffer: A = 128 rows x 32 us (8KB), B = 8KB frag-order; x2 buffers
  __shared__ __align__(16) ushort lds[16384];

  // zero A pad rows (49..63, 113..127) in both buffers
  for (int i = t; i < 2 * 30 * 32; i += 256) {
    int buf = i >= 960;
    int r2 = i - buf * 960;
    int rr = r2 >> 5;
    int row = (rr < 15) ? (49 + rr) : (98 + rr);  // 49..63 then 113..127
    lds[buf * 8192 + row * 32 + (i & 31)] = 0;
  }

  const int arow = lane & 15, g = lane >> 4;
  int srow0 = w * 16 + (lane >> 2);
  int cL = lane & 3;
  const ushort* wBbase = wqkvB + (size_t)nb * 16 * 4096;

  // stage step 0 -> buf 0
  {
#pragma unroll
    for (int i = 0; i < 2; i++) {
      int row = i * 64 + srow0;
      int n = row & 63, bb = b0 + (row >> 6);
      int cG = cL ^ ((row >> 1) & 3);
      if (n < NTOK)
        GLOAD_LDS16(xnW + ((size_t)bb * NTOK + n) * CH + cG * 8, lds + (i * 64 + w * 16) * 32);
    }
    GLOAD_LDS16(wBbase + (w * 2 + 0) * 512 + lane * 8, lds + 4096 + (w * 2 + 0) * 512);
    GLOAD_LDS16(wBbase + (w * 2 + 1) * 512 + lane * 8, lds + 4096 + (w * 2 + 1) * 512);
  }
  __syncthreads();

  f32x4 acc[4][4];
#pragma unroll
  for (int mt = 0; mt < 4; mt++)
#pragma unroll
    for (int nt = 0; nt < 4; nt++) acc[mt][nt] = (f32x4){0.f, 0.f, 0.f, 0.f};

  int cur = 0;
  for (int step = 0; step < 16; ++step) {
    if (step < 15) {
      int nxt = cur ^ 1, kk = step + 1;
#pragma unroll
      for (int i = 0; i < 2; i++) {
        int row = i * 64 + srow0;
        int n = row & 63, bb = b0 + (row >> 6);
        int cG = cL ^ ((row >> 1) & 3);
        if (n < NTOK)
          GLOAD_LDS16(xnW + ((size_t)bb * NTOK + n) * CH + kk * 32 + cG * 8,
                      lds + nxt * 8192 + (i * 64 + w * 16) * 32);
      }
      const ushort* wp = wBbase + (size_t)kk * 4096;
      GLOAD_LDS16(wp + (w * 2 + 0) * 512 + lane * 8, lds + nxt * 8192 + 4096 + (w * 2 + 0) * 512);
      GLOAD_LDS16(wp + (w * 2 + 1) * 512 + lane * 8, lds + nxt * 8192 + 4096 + (w * 2 + 1) * 512);
    }
    const ushort* lA = lds + cur * 8192;
    const ushort* lB = lds + cur * 8192 + 4096;
    bf16x8 bfr[4], afr[4];
#pragma unroll
    for (int nt = 0; nt < 4; nt++)
      bfr[nt] = *(const bf16x8*)&lB[((wn * 4 + nt) * 64 + lane) * 8];
#pragma unroll
    for (int mt = 0; mt < 4; mt++) {
      int row = wm * 64 + mt * 16 + arow;
      afr[mt] = *(const bf16x8*)&lA[row * 32 + (g ^ ((row >> 1) & 3)) * 8];
    }
#pragma unroll
    for (int mt = 0; mt < 4; mt++)
#pragma unroll
      for (int nt = 0; nt < 4; nt++) acc[mt][nt] = MFMA16(afr[mt], bfr[nt], acc[mt][nt]);
    __syncthreads();
    cur ^= 1;
  }

  // epilogue: per batch-half through LDS
  ushort(*oL)[136] = (ushort(*)[136])lds;
  int h0 = (nb & 3) * 2;
  int sct = nb >> 2;  // 0=q 1=k 2=v
#pragma unroll
  for (int hh = 0; hh < 2; hh++) {
    if (wm == hh) {
#pragma unroll
      for (int mt = 0; mt < 4; mt++)
#pragma unroll
        for (int nt = 0; nt < 4; nt++)
#pragma unroll
          for (int r = 0; r < 4; r++) {
            int rn = mt * 16 + 4 * g + r;
            oL[rn][wn * 64 + nt * 16 + arow] = f2bf(acc[mt][nt][r]);
          }
    }
    __syncthreads();
    int b = b0 + hh;
    if (sct < 2) {
      ushort* dst = (sct == 0 ? qW : kW);
      for (int i = t; i < NTOK * 16; i += 256) {
        int n = i >> 4, c8 = i & 15;
        int h = h0 + (c8 >> 3);
        *(uint4*)(dst + (size_t)(b * 8 + h) * (NTOK * 64) + n * 64 + (c8 & 7) * 8) =
            *(const uint4*)&oL[n][c8 * 8];
      }
    } else {
      for (int i = t; i < 128 * 8; i += 256) {
        int col = i >> 3, n8 = i & 7;
        int h = h0 + (col >> 6), d = col & 63;
        ushort tmp[8];
#pragma unroll
        for (int jj = 0; jj < 8; jj++) tmp[jj] = oL[n8 * 8 + jj][col];  // pad rows are exact zeros
        *(uint4*)(vW + (size_t)(b * 8 + h) * 4096 + d * 64 + n8 * 8) = *(const uint4*)tmp;
      }
    }
    __syncthreads();
  }
}

// ---------------- Kernel 3: attention, one head per wave, zero block barriers ----------------
__global__ __launch_bounds__(512, 4) void attn2(const ushort* __restrict__ qW,
                                                const ushort* __restrict__ kW,
                                                const ushort* __restrict__ vW,
                                                const float* __restrict__ biasP,
                                                ushort* __restrict__ aoW) {
  int b = blockIdx.x;
  int t = threadIdx.x;
  int lane = t & 63;
  int h = t >> 6;

  __shared__ ushort pL[8][64][72];
  ushort(*pl)[72] = pL[h];

  const int c = lane & 15, g = lane >> 4;
  const ushort* qb = qW + (size_t)(b * 8 + h) * NTOK * 64;
  const ushort* kb = kW + (size_t)(b * 8 + h) * NTOK * 64;
  const ushort* vb = vW + (size_t)(b * 8 + h) * 64 * 64;
  const float* bp = biasP + h * 64 * 64;

  f32x4 s[4][4];
#pragma unroll
  for (int mt = 0; mt < 4; mt++)
#pragma unroll
    for (int nt = 0; nt < 4; nt++) s[mt][nt] = (f32x4){0.f, 0.f, 0.f, 0.f};
#pragma unroll
  for (int ks = 0; ks < 2; ks++) {
    bf16x8 kf[4];
#pragma unroll
    for (int nt = 0; nt < 4; nt++)
      kf[nt] = *(const bf16x8*)(kb + (size_t)(nt * 16 + c) * 64 + ks * 32 + g * 8);
#pragma unroll
    for (int mt = 0; mt < 4; mt++) {
      bf16x8 qf = *(const bf16x8*)(qb + (size_t)(mt * 16 + c) * 64 + ks * 32 + g * 8);
#pragma unroll
      for (int nt = 0; nt < 4; nt++) s[mt][nt] = MFMA16(qf, kf[nt], s[mt][nt]);
    }
  }
#pragma unroll
  for (int mt = 0; mt < 4; mt++)
#pragma unroll
    for (int nt = 0; nt < 4; nt++)
#pragma unroll
      for (int r = 0; r < 4; r++) {
        int n = mt * 16 + 4 * g + r;
        int m = nt * 16 + c;
        s[mt][nt][r] = s[mt][nt][r] * 0.125f + bp[n * 64 + m];
      }

#pragma unroll
  for (int mt = 0; mt < 4; mt++)
#pragma unroll
    for (int r = 0; r < 4; r++) {
      float mx = fmaxf(fmaxf(s[mt][0][r], s[mt][1][r]), fmaxf(s[mt][2][r], s[mt][3][r]));
      mx = fmaxf(mx, __shfl_xor(mx, 1));
      mx = fmaxf(mx, __shfl_xor(mx, 2));
      mx = fmaxf(mx, __shfl_xor(mx, 4));
      mx = fmaxf(mx, __shfl_xor(mx, 8));
      float p0 = __expf(s[mt][0][r] - mx);
      float p1 = __expf(s[mt][1][r] - mx);
      float p2 = __expf(s[mt][2][r] - mx);
      float p3 = __expf(s[mt][3][r] - mx);
      float sum = p0 + p1 + p2 + p3;
      sum += __shfl_xor(sum, 1);
      sum += __shfl_xor(sum, 2);
      sum += __shfl_xor(sum, 4);
      sum += __shfl_xor(sum, 8);
      float rinv = 1.f / sum;
      int n = mt * 16 + 4 * g + r;
      pl[n][0 * 16 + c] = f2bf(p0 * rinv);
      pl[n][1 * 16 + c] = f2bf(p1 * rinv);
      pl[n][2 * 16 + c] = f2bf(p2 * rinv);
      pl[n][3 * 16 + c] = f2bf(p3 * rinv);
    }

  f32x4 o[4][4];
#pragma unroll
  for (int mt = 0; mt < 4; mt++)
#pragma unroll
    for (int nt = 0; nt < 4; nt++) o[mt][nt] = (f32x4){0.f, 0.f, 0.f, 0.f};
#pragma unroll
  for (int ks = 0; ks < 2; ks++) {
    bf16x8 vf[4];
#pragma unroll
    for (int nt = 0; nt < 4; nt++)
      vf[nt] = *(const bf16x8*)(vb + (size_t)(nt * 16 + c) * 64 + ks * 32 + g * 8);
#pragma unroll
    for (int mt = 0; mt < 4; mt++) {
      bf16x8 pf = *(const bf16x8*)&pl[mt * 16 + c][ks * 32 + g * 8];
#pragma unroll
      for (int nt = 0; nt < 4; nt++) o[mt][nt] = MFMA16(pf, vf[nt], o[mt][nt]);
    }
  }

#pragma unroll
  for (int mt = 0; mt < 4; mt++)
#pragma unroll
    for (int nt = 0; nt < 4; nt++)
#pragma unroll
      for (int r = 0; r < 4; r++) {
        int n = mt * 16 + 4 * g + r;
        pl[n][nt * 16 + c] = f2bf(o[mt][nt][r]);
      }
  ushort* ao = aoW + (size_t)b * NTOK * CH + h * 64;
  for (int i = lane; i < NTOK * 8; i += 64) {
    int row = i >> 3, c8 = i & 7;
    *(uint4*)(ao + (size_t)row * CH + c8 * 8) = *(const uint4*)&pl[row][c8 * 8];
  }
}

// ---------------- Kernel 4: out-proj GEMM (128x128 tile) + bias + residual ----------------
__global__ __launch_bounds__(256, 4) void proj_kernel(const ushort* __restrict__ aoW,
                                                      const ushort* __restrict__ woutF,
                                                      const float* __restrict__ b_out,
                                                      const float* __restrict__ x,
                                                      float* __restrict__ out) {
  int bid = blockIdx.x;
  int f = (bid & 7) * 512 + (bid >> 3);  // bijective (4096 = 8*512)
  int mb = f >> 2, nbp = f & 3;
  int b0 = mb * 2;
  int t = threadIdx.x, lane = t & 63, w = t >> 6;
  int wm = w >> 1, wn = w & 1;

  __shared__ __align__(16) char ldsraw[33792];  // staging 32KB; epilogue f32 [64][132]
  ushort* lds = (ushort*)ldsraw;
  float(*oL)[132] = (float(*)[132])ldsraw;

  for (int i = t; i < 2 * 30 * 32; i += 256) {
    int buf = i >= 960;
    int r2 = i - buf * 960;
    int rr = r2 >> 5;
    int row = (rr < 15) ? (49 + rr) : (98 + rr);
    lds[buf * 8192 + row * 32 + (i & 31)] = 0;
  }

  const int arow = lane & 15, g = lane >> 4;
  int srow0 = w * 16 + (lane >> 2);
  int cL = lane & 3;

  {
#pragma unroll
    for (int i = 0; i < 2; i++) {
      int row = i * 64 + srow0;
      int n = row & 63, bb = b0 + (row >> 6);
      int cG = cL ^ ((row >> 1) & 3);
      if (n < NTOK)
        GLOAD_LDS16(aoW + ((size_t)bb * NTOK + n) * CH + cG * 8, lds + (i * 64 + w * 16) * 32);
    }
    GLOAD_LDS16(woutF + ((size_t)(nbp * 8 + w * 2 + 0) * 16) * 512 + lane * 8,
                lds + 4096 + (w * 2 + 0) * 512);
    GLOAD_LDS16(woutF + ((size_t)(nbp * 8 + w * 2 + 1) * 16) * 512 + lane * 8,
                lds + 4096 + (w * 2 + 1) * 512);
  }
  __syncthreads();

  f32x4 acc[4][4];
#pragma unroll
  for (int mt = 0; mt < 4; mt++)
#pragma unroll
    for (int nt = 0; nt < 4; nt++) acc[mt][nt] = (f32x4){0.f, 0.f, 0.f, 0.f};

  int cur = 0;
  for (int step = 0; step < 16; ++step) {
    if (step < 15) {
      int nxt = cur ^ 1, kk = step + 1;
#pragma unroll
      for (int i = 0; i < 2; i++) {
        int row = i * 64 + srow0;
        int n = row & 63, bb = b0 + (row >> 6);
        int cG = cL ^ ((row >> 1) & 3);
        if (n < NTOK)
          GLOAD_LDS16(aoW + ((size_t)bb * NTOK + n) * CH + kk * 32 + cG * 8,
                      lds + nxt * 8192 + (i * 64 + w * 16) * 32);
      }
      GLOAD_LDS16(woutF + ((size_t)((nbp * 8 + w * 2 + 0) * 16 + kk)) * 512 + lane * 8,
                  lds + nxt * 8192 + 4096 + (w * 2 + 0) * 512);
      GLOAD_LDS16(woutF + ((size_t)((nbp * 8 + w * 2 + 1) * 16 + kk)) * 512 + lane * 8,
                  lds + nxt * 8192 + 4096 + (w * 2 + 1) * 512);
    }
    const ushort* lA = lds + cur * 8192;
    const ushort* lB = lds + cur * 8192 + 4096;
    bf16x8 bfr[4], afr[4];
#pragma unroll
    for (int nt = 0; nt < 4; nt++)
      bfr[nt] = *(const bf16x8*)&lB[((wn * 4 + nt) * 64 + lane) * 8];
#pragma unroll
    for (int mt = 0; mt < 4; mt++) {
      int row = wm * 64 + mt * 16 + arow;
      afr[mt] = *(const bf16x8*)&lA[row * 32 + (g ^ ((row >> 1) & 3)) * 8];
    }
#pragma unroll
    for (int mt = 0; mt < 4; mt++)
#pragma unroll
      for (int nt = 0; nt < 4; nt++) acc[mt][nt] = MFMA16(afr[mt], bfr[nt], acc[mt][nt]);
    __syncthreads();
    cur ^= 1;
  }

  const float* bo = b_out + nbp * 128;
#pragma unroll
  for (int hh = 0; hh < 2; hh++) {
    if (wm == hh) {
#pragma unroll
      for (int mt = 0; mt < 4; mt++)
#pragma unroll
        for (int nt = 0; nt < 4; nt++)
#pragma unroll
          for (int r = 0; r < 4; r++) {
            int rn = mt * 16 + 4 * g + r;
            if (rn < NTOK) oL[rn][wn * 64 + nt * 16 + arow] = acc[mt][nt][r];
          }
    }
    __syncthreads();
    int b = b0 + hh;
    const float4* x4 = (const float4*)(x + ((size_t)b * CH + nbp * 128) * NTOK);
    float4* o4 = (float4*)(out + ((size_t)b * CH + nbp * 128) * NTOK);
    for (int i = t; i < 1568; i += 256) {
      float4 xv = x4[i];
      float4 ov;
      int lf = i * 4;
#pragma unroll
      for (int e = 0; e < 4; e++) {
        int cl = (lf + e) / NTOK, n = (lf + e) - cl * NTOK;
        ((float*)&ov)[e] = oL[n][cl] + bo[cl] + ((const float*)&xv)[e];
      }
      o4[i] = ov;
    }
    __syncthreads();
  }
}

extern "C" void kernel_launch(void* const* d_in, const int* in_sizes, int n_in,
                              void* d_out, int out_size, void* d_ws, size_t ws_size,
                              hipStream_t stream) {
  const float* x = (const float*)d_in[0];
  const float* gamma = (const float*)d_in[1];
  const float* beta = (const float*)d_in[2];
  const float* w_qkv = (const float*)d_in[3];
  const float* rel = (const float*)d_in[4];
  const float* w_out = (const float*)d_in[5];
  const float* b_out = (const float*)d_in[6];
  float* out = (float*)d_out;

  char* ws = (char*)d_ws;
  size_t off = 0;
  ushort* wqkvB = (ushort*)(ws + off); off += (size_t)12 * 16 * 4096 * 2;
  ushort* woutF = (ushort*)(ws + off); off += (size_t)512 * 512 * 2;
  float* biasP = (float*)(ws + off);   off += (size_t)NHEAD * 64 * 64 * 4;
  ushort* qW = (ushort*)(ws + off);    off += ((size_t)BATCH * 8 * NTOK * 64 + 1024) * 2;
  ushort* kW = (ushort*)(ws + off);    off += ((size_t)BATCH * 8 * NTOK * 64 + 1024) * 2;
  ushort* vW = (ushort*)(ws + off);    off += (size_t)BATCH * 8 * 64 * 64 * 2;
  ushort* xnW = (ushort*)(ws + off);   off += (size_t)BATCH * NTOK * CH * 2;
  ushort* aoW = xnW;  // alias: xn dead after qkv_gemm
  (void)ws_size;

  prep_kernel<<<1024, 256, 0, stream>>>(w_qkv, w_out, rel, wqkvB, woutF, biasP);
  ln_kernel<<<BATCH, 256, 0, stream>>>(x, gamma, beta, xnW);
  qkv_gemm<<<BATCH / 2 * 12, 256, 0, stream>>>(xnW, wqkvB, qW, kW, vW);
  attn2<<<BATCH, 512, 0, stream>>>(qW, kW, vW, biasP, aoW);
  proj_kernel<<<BATCH / 2 * 4, 256, 0, stream>>>(aoW, woutF, b_out, x, out);
}

// Round 6
// 640.586 us; speedup vs baseline: 2.4938x; 1.0360x over previous
//
#include <hip/hip_runtime.h>

#define BATCH 2048
#define CH 512
#define NTOK 49
#define NHEAD 8
#define DHEAD 64

typedef __attribute__((ext_vector_type(8))) short bf16x8;
typedef __attribute__((ext_vector_type(4))) float f32x4;

__device__ __forceinline__ ushort f2bf(float f) {
  union { float f; unsigned u; } v; v.f = f;
  unsigned r = v.u + 0x7fffu + ((v.u >> 16) & 1u);
  return (ushort)(r >> 16);
}

__device__ __forceinline__ float bf2f(ushort u) {
  union { unsigned u; float f; } v; v.u = ((unsigned)u) << 16;
  return v.f;
}

#define MFMA16(a, b, c) __builtin_amdgcn_mfma_f32_16x16x32_bf16((a), (b), (c), 0, 0, 0)

#define GLOAD_LDS16(gsrc, ldst)                                                  \
  __builtin_amdgcn_global_load_lds((const __attribute__((address_space(1))) void*)(gsrc), \
                                   (__attribute__((address_space(3))) void*)(ldst), 16, 0, 0)

// ---------------- Kernel 0: packed weights + padded bias table ----------------
// wqkvB[nb][kk] = 8KB block [cbs(8)][lane(64)][8]: o = nb*128+cbs*16+(lane&15), c = kk*32+(lane>>4)*8+j
// woutF[cb][ks][lane][8]: o = cb*16+(lane&15), c = ks*32+(lane>>4)*8+j
// biasP[h][64][64] f32: (n<49 && m<49) ? swin_bias : -1e30
__global__ void prep_kernel(const float* __restrict__ w_qkv, const float* __restrict__ w_out,
                            const float* __restrict__ rel, ushort* __restrict__ wqkvB,
                            ushort* __restrict__ woutF, float* __restrict__ biasP) {
  int tid = blockIdx.x * blockDim.x + threadIdx.x;
  int stride = gridDim.x * blockDim.x;
  for (int i = tid; i < 12 * 16 * 8 * 64 * 8; i += stride) {
    int j = i & 7, lane = (i >> 3) & 63, cbs = (i >> 9) & 7, kk = (i >> 12) & 15, nb = i >> 16;
    int o = nb * 128 + cbs * 16 + (lane & 15);
    int c = kk * 32 + (lane >> 4) * 8 + j;
    wqkvB[i] = f2bf(w_qkv[c * 1536 + o]);
  }
  for (int i = tid; i < 32 * 16 * 64 * 8; i += stride) {
    int j = i & 7, lane = (i >> 3) & 63, ks = (i >> 9) & 15, cb = i >> 13;
    int o = cb * 16 + (lane & 15);
    int c = ks * 32 + (lane >> 4) * 8 + j;
    woutF[i] = f2bf(w_out[c * 512 + o]);
  }
  for (int i = tid; i < NHEAD * 64 * 64; i += stride) {
    int h = i >> 12, n = (i >> 6) & 63, m = i & 63;
    float v = -1e30f;
    if (n < NTOK && m < NTOK) {
      int dh = n / 7 - m / 7 + 6;
      int dw = n % 7 - m % 7 + 6;
      v = rel[(dh * 13 + dw) * 8 + h];
    }
    biasP[i] = v;
  }
}

// ---------------- Kernel 1: one-pass LayerNorm, x[b][c][n] f32 -> xn bf16 [b][n][c] ----------------
// Stage x once as bf16 in LDS (50KB, 3 blocks/CU); stats + normalize from LDS.
__global__ __launch_bounds__(256) void ln_kernel(const float* __restrict__ x,
                                                 const float* __restrict__ gamma,
                                                 const float* __restrict__ beta,
                                                 ushort* __restrict__ xnW) {
  int b = blockIdx.x;
  int t = threadIdx.x;
  __shared__ ushort xsb[CH][NTOK];
  __shared__ float muL[64], rsL[64];
  const float4* x4 = (const float4*)(x + (size_t)b * CH * NTOK);
  for (int i4 = t; i4 < CH * NTOK / 4; i4 += 256) {
    float4 v = x4[i4];
    int lf = i4 * 4;
#pragma unroll
    for (int e = 0; e < 4; e++) {
      int idx = lf + e;
      int c = idx / NTOK, n = idx - c * NTOK;
      xsb[c][n] = f2bf(((const float*)&v)[e]);
    }
  }
  __syncthreads();
  int row = t >> 2, sub = t & 3;
  float s = 0.f, s2 = 0.f;
  if (row < NTOK) {
    for (int c = sub; c < CH; c += 4) {
      float v = bf2f(xsb[c][row]);
      s += v;
      s2 += v * v;
    }
  }
  s += __shfl_xor(s, 1);
  s += __shfl_xor(s, 2);
  s2 += __shfl_xor(s2, 1);
  s2 += __shfl_xor(s2, 2);
  if (sub == 0 && row < NTOK) {
    float m = s * (1.f / CH);
    muL[row] = m;
    rsL[row] = rsqrtf(s2 * (1.f / CH) - m * m + 1e-5f);
  }
  __syncthreads();
  ushort* dst = xnW + (size_t)b * NTOK * CH;
  for (int i = t; i < NTOK * 64; i += 256) {
    int n = i >> 6, c0 = (i & 63) * 8;
    float mu = muL[n], rs = rsL[n];
    ushort tmp[8];
#pragma unroll
    for (int j = 0; j < 8; j++) {
      int c = c0 + j;
      tmp[j] = f2bf((bf2f(xsb[c][n]) - mu) * rs * gamma[c] + beta[c]);
    }
    *(uint4*)(dst + (size_t)n * CH + c0) = *(const uint4*)tmp;
  }
}

// ---------------- Kernel 2: QKV GEMM, 128x128 tile; A via LDS dbuf, B direct from L2 ----------------
__global__ __launch_bounds__(256, 4) void qkv_gemm(const ushort* __restrict__ xnW,
                                                   const ushort* __restrict__ wqkvB,
                                                   ushort* __restrict__ qW,
                                                   ushort* __restrict__ kW,
                                                   ushort* __restrict__ vW) {
  int bid = blockIdx.x;
  int f = (bid & 7) * 1536 + (bid >> 3);  // bijective XCD swizzle (12288 = 8*1536)
  int mb = f / 12, nb = f - mb * 12;
  int b0 = mb * 2;
  int t = threadIdx.x, lane = t & 63, w = t >> 6;
  int wm = w >> 1, wn = w & 1;

  // staging: 2 buffers x A[128][32] (8KB each); epilogue reuses as oL[64][136]
  __shared__ __align__(16) ushort lds[8704];

  // zero A pad rows (49..63, 113..127) in both buffers
  for (int i = t; i < 2 * 30 * 32; i += 256) {
    int buf = i >= 960;
    int r2 = i - buf * 960;
    int rr = r2 >> 5;
    int row = (rr < 15) ? (49 + rr) : (98 + rr);
    lds[buf * 4096 + row * 32 + (i & 31)] = 0;
  }

  const int arow = lane & 15, g = lane >> 4;
  int srow0 = w * 16 + (lane >> 2);
  int cL = lane & 3;
  const ushort* wBbase = wqkvB + (size_t)nb * 16 * 4096;

  // stage step 0 -> buf 0
  {
#pragma unroll
    for (int i = 0; i < 2; i++) {
      int row = i * 64 + srow0;
      int n = row & 63, bb = b0 + (row >> 6);
      int cG = cL ^ ((row >> 1) & 3);
      if (n < NTOK)
        GLOAD_LDS16(xnW + ((size_t)bb * NTOK + n) * CH + cG * 8, lds + (i * 64 + w * 16) * 32);
    }
  }
  __syncthreads();

  f32x4 acc[4][4];
#pragma unroll
  for (int mt = 0; mt < 4; mt++)
#pragma unroll
    for (int nt = 0; nt < 4; nt++) acc[mt][nt] = (f32x4){0.f, 0.f, 0.f, 0.f};

  int cur = 0;
  for (int step = 0; step < 16; ++step) {
    // B-frags straight from global (L2-hot, frag-packed, 1KB coalesced per frag)
    const ushort* wp = wBbase + (size_t)step * 4096 + (wn * 4) * 512 + lane * 8;
    bf16x8 bfr[4];
#pragma unroll
    for (int nt = 0; nt < 4; nt++) bfr[nt] = *(const bf16x8*)(wp + nt * 512);
    // prefetch next A tile
    if (step < 15) {
      int nxt = cur ^ 1, kk = step + 1;
#pragma unroll
      for (int i = 0; i < 2; i++) {
        int row = i * 64 + srow0;
        int n = row & 63, bb = b0 + (row >> 6);
        int cG = cL ^ ((row >> 1) & 3);
        if (n < NTOK)
          GLOAD_LDS16(xnW + ((size_t)bb * NTOK + n) * CH + kk * 32 + cG * 8,
                      lds + nxt * 4096 + (i * 64 + w * 16) * 32);
      }
    }
    const ushort* lA = lds + cur * 4096;
    bf16x8 afr[4];
#pragma unroll
    for (int mt = 0; mt < 4; mt++) {
      int row = wm * 64 + mt * 16 + arow;
      afr[mt] = *(const bf16x8*)&lA[row * 32 + (g ^ ((row >> 1) & 3)) * 8];
    }
#pragma unroll
    for (int mt = 0; mt < 4; mt++)
#pragma unroll
      for (int nt = 0; nt < 4; nt++) acc[mt][nt] = MFMA16(afr[mt], bfr[nt], acc[mt][nt]);
    __syncthreads();
    cur ^= 1;
  }

  // epilogue: per batch-half through LDS
  ushort(*oL)[136] = (ushort(*)[136])lds;
  int h0 = (nb & 3) * 2;
  int sct = nb >> 2;  // 0=q 1=k 2=v
#pragma unroll
  for (int hh = 0; hh < 2; hh++) {
    if (wm == hh) {
#pragma unroll
      for (int mt = 0; mt < 4; mt++)
#pragma unroll
        for (int nt = 0; nt < 4; nt++)
#pragma unroll
          for (int r = 0; r < 4; r++) {
            int rn = mt * 16 + 4 * g + r;
            oL[rn][wn * 64 + nt * 16 + arow] = f2bf(acc[mt][nt][r]);
          }
    }
    __syncthreads();
    int b = b0 + hh;
    if (sct < 2) {
      ushort* dst = (sct == 0 ? qW : kW);
      for (int i = t; i < NTOK * 16; i += 256) {
        int n = i >> 4, c8 = i & 15;
        int h = h0 + (c8 >> 3);
        *(uint4*)(dst + (size_t)(b * 8 + h) * (NTOK * 64) + n * 64 + (c8 & 7) * 8) =
            *(const uint4*)&oL[n][c8 * 8];
      }
    } else {
      for (int i = t; i < 128 * 8; i += 256) {
        int col = i >> 3, n8 = i & 7;
        int h = h0 + (col >> 6), d = col & 63;
        ushort tmp[8];
#pragma unroll
        for (int jj = 0; jj < 8; jj++) tmp[jj] = oL[n8 * 8 + jj][col];  // pad rows are exact zeros
        *(uint4*)(vW + (size_t)(b * 8 + h) * 4096 + d * 64 + n8 * 8) = *(const uint4*)tmp;
      }
    }
    __syncthreads();
  }
}

// ---------------- Kernel 3: attention, one head per wave, zero block barriers ----------------
__global__ __launch_bounds__(512, 4) void attn2(const ushort* __restrict__ qW,
                                                const ushort* __restrict__ kW,
                                                const ushort* __restrict__ vW,
                                                const float* __restrict__ biasP,
                                                ushort* __restrict__ aoW) {
  int b = blockIdx.x;
  int t = threadIdx.x;
  int lane = t & 63;
  int h = t >> 6;

  __shared__ ushort pL[8][64][72];
  ushort(*pl)[72] = pL[h];

  const int c = lane & 15, g = lane >> 4;
  const ushort* qb = qW + (size_t)(b * 8 + h) * NTOK * 64;
  const ushort* kb = kW + (size_t)(b * 8 + h) * NTOK * 64;
  const ushort* vb = vW + (size_t)(b * 8 + h) * 64 * 64;
  const float* bp = biasP + h * 64 * 64;

  f32x4 s[4][4];
#pragma unroll
  for (int mt = 0; mt < 4; mt++)
#pragma unroll
    for (int nt = 0; nt < 4; nt++) s[mt][nt] = (f32x4){0.f, 0.f, 0.f, 0.f};
#pragma unroll
  for (int ks = 0; ks < 2; ks++) {
    bf16x8 kf[4];
#pragma unroll
    for (int nt = 0; nt < 4; nt++)
      kf[nt] = *(const bf16x8*)(kb + (size_t)(nt * 16 + c) * 64 + ks * 32 + g * 8);
#pragma unroll
    for (int mt = 0; mt < 4; mt++) {
      bf16x8 qf = *(const bf16x8*)(qb + (size_t)(mt * 16 + c) * 64 + ks * 32 + g * 8);
#pragma unroll
      for (int nt = 0; nt < 4; nt++) s[mt][nt] = MFMA16(qf, kf[nt], s[mt][nt]);
    }
  }
#pragma unroll
  for (int mt = 0; mt < 4; mt++)
#pragma unroll
    for (int nt = 0; nt < 4; nt++)
#pragma unroll
      for (int r = 0; r < 4; r++) {
        int n = mt * 16 + 4 * g + r;
        int m = nt * 16 + c;
        s[mt][nt][r] = s[mt][nt][r] * 0.125f + bp[n * 64 + m];
      }

#pragma unroll
  for (int mt = 0; mt < 4; mt++)
#pragma unroll
    for (int r = 0; r < 4; r++) {
      float mx = fmaxf(fmaxf(s[mt][0][r], s[mt][1][r]), fmaxf(s[mt][2][r], s[mt][3][r]));
      mx = fmaxf(mx, __shfl_xor(mx, 1));
      mx = fmaxf(mx, __shfl_xor(mx, 2));
      mx = fmaxf(mx, __shfl_xor(mx, 4));
      mx = fmaxf(mx, __shfl_xor(mx, 8));
      float p0 = __expf(s[mt][0][r] - mx);
      float p1 = __expf(s[mt][1][r] - mx);
      float p2 = __expf(s[mt][2][r] - mx);
      float p3 = __expf(s[mt][3][r] - mx);
      float sum = p0 + p1 + p2 + p3;
      sum += __shfl_xor(sum, 1);
      sum += __shfl_xor(sum, 2);
      sum += __shfl_xor(sum, 4);
      sum += __shfl_xor(sum, 8);
      float rinv = 1.f / sum;
      int n = mt * 16 + 4 * g + r;
      pl[n][0 * 16 + c] = f2bf(p0 * rinv);
      pl[n][1 * 16 + c] = f2bf(p1 * rinv);
      pl[n][2 * 16 + c] = f2bf(p2 * rinv);
      pl[n][3 * 16 + c] = f2bf(p3 * rinv);
    }

  f32x4 o[4][4];
#pragma unroll
  for (int mt = 0; mt < 4; mt++)
#pragma unroll
    for (int nt = 0; nt < 4; nt++) o[mt][nt] = (f32x4){0.f, 0.f, 0.f, 0.f};
#pragma unroll
  for (int ks = 0; ks < 2; ks++) {
    bf16x8 vf[4];
#pragma unroll
    for (int nt = 0; nt < 4; nt++)
      vf[nt] = *(const bf16x8*)(vb + (size_t)(nt * 16 + c) * 64 + ks * 32 + g * 8);
#pragma unroll
    for (int mt = 0; mt < 4; mt++) {
      bf16x8 pf = *(const bf16x8*)&pl[mt * 16 + c][ks * 32 + g * 8];
#pragma unroll
      for (int nt = 0; nt < 4; nt++) o[mt][nt] = MFMA16(pf, vf[nt], o[mt][nt]);
    }
  }

#pragma unroll
  for (int mt = 0; mt < 4; mt++)
#pragma unroll
    for (int nt = 0; nt < 4; nt++)
#pragma unroll
      for (int r = 0; r < 4; r++) {
        int n = mt * 16 + 4 * g + r;
        pl[n][nt * 16 + c] = f2bf(o[mt][nt][r]);
      }
  ushort* ao = aoW + (size_t)b * NTOK * CH + h * 64;
  for (int i = lane; i < NTOK * 8; i += 64) {
    int row = i >> 3, c8 = i & 7;
    *(uint4*)(ao + (size_t)row * CH + c8 * 8) = *(const uint4*)&pl[row][c8 * 8];
  }
}

// ---------------- Kernel 4: out-proj GEMM; A via LDS dbuf, B direct from L2 ----------------
__global__ __launch_bounds__(256, 4) void proj_kernel(const ushort* __restrict__ aoW,
                                                      const ushort* __restrict__ woutF,
                                                      const float* __restrict__ b_out,
                                                      const float* __restrict__ x,
                                                      float* __restrict__ out) {
  int bid = blockIdx.x;
  int f = (bid & 7) * 512 + (bid >> 3);  // bijective (4096 = 8*512)
  int mb = f >> 2, nbp = f & 3;
  int b0 = mb * 2;
  int t = threadIdx.x, lane = t & 63, w = t >> 6;
  int wm = w >> 1, wn = w & 1;

  __shared__ __align__(16) char ldsraw[33792];  // staging 16KB; epilogue f32 [64][132]
  ushort* lds = (ushort*)ldsraw;
  float(*oL)[132] = (float(*)[132])ldsraw;

  for (int i = t; i < 2 * 30 * 32; i += 256) {
    int buf = i >= 960;
    int r2 = i - buf * 960;
    int rr = r2 >> 5;
    int row = (rr < 15) ? (49 + rr) : (98 + rr);
    lds[buf * 4096 + row * 32 + (i & 31)] = 0;
  }

  const int arow = lane & 15, g = lane >> 4;
  int srow0 = w * 16 + (lane >> 2);
  int cL = lane & 3;

  {
#pragma unroll
    for (int i = 0; i < 2; i++) {
      int row = i * 64 + srow0;
      int n = row & 63, bb = b0 + (row >> 6);
      int cG = cL ^ ((row >> 1) & 3);
      if (n < NTOK)
        GLOAD_LDS16(aoW + ((size_t)bb * NTOK + n) * CH + cG * 8, lds + (i * 64 + w * 16) * 32);
    }
  }
  __syncthreads();

  f32x4 acc[4][4];
#pragma unroll
  for (int mt = 0; mt < 4; mt++)
#pragma unroll
    for (int nt = 0; nt < 4; nt++) acc[mt][nt] = (f32x4){0.f, 0.f, 0.f, 0.f};

  int cur = 0;
  for (int step = 0; step < 16; ++step) {
    const ushort* wp = woutF + ((size_t)(nbp * 8 + wn * 4) * 16 + step) * 512 + lane * 8;
    bf16x8 bfr[4];
#pragma unroll
    for (int nt = 0; nt < 4; nt++) bfr[nt] = *(const bf16x8*)(wp + (size_t)nt * 16 * 512);
    if (step < 15) {
      int nxt = cur ^ 1, kk = step + 1;
#pragma unroll
      for (int i = 0; i < 2; i++) {
        int row = i * 64 + srow0;
        int n = row & 63, bb = b0 + (row >> 6);
        int cG = cL ^ ((row >> 1) & 3);
        if (n < NTOK)
          GLOAD_LDS16(aoW + ((size_t)bb * NTOK + n) * CH + kk * 32 + cG * 8,
                      lds + nxt * 4096 + (i * 64 + w * 16) * 32);
      }
    }
    const ushort* lA = lds + cur * 4096;
    bf16x8 afr[4];
#pragma unroll
    for (int mt = 0; mt < 4; mt++) {
      int row = wm * 64 + mt * 16 + arow;
      afr[mt] = *(const bf16x8*)&lA[row * 32 + (g ^ ((row >> 1) & 3)) * 8];
    }
#pragma unroll
    for (int mt = 0; mt < 4; mt++)
#pragma unroll
      for (int nt = 0; nt < 4; nt++) acc[mt][nt] = MFMA16(afr[mt], bfr[nt], acc[mt][nt]);
    __syncthreads();
    cur ^= 1;
  }

  const float* bo = b_out + nbp * 128;
#pragma unroll
  for (int hh = 0; hh < 2; hh++) {
    if (wm == hh) {
#pragma unroll
      for (int mt = 0; mt < 4; mt++)
#pragma unroll
        for (int nt = 0; nt < 4; nt++)
#pragma unroll
          for (int r = 0; r < 4; r++) {
            int rn = mt * 16 + 4 * g + r;
            if (rn < NTOK) oL[rn][wn * 64 + nt * 16 + arow] = acc[mt][nt][r];
          }
    }
    __syncthreads();
    int b = b0 + hh;
    const float4* x4 = (const float4*)(x + ((size_t)b * CH + nbp * 128) * NTOK);
    float4* o4 = (float4*)(out + ((size_t)b * CH + nbp * 128) * NTOK);
    for (int i = t; i < 1568; i += 256) {
      float4 xv = x4[i];
      float4 ov;
      int lf = i * 4;
#pragma unroll
      for (int e = 0; e < 4; e++) {
        int cl = (lf + e) / NTOK, n = (lf + e) - cl * NTOK;
        ((float*)&ov)[e] = oL[n][cl] + bo[cl] + ((const float*)&xv)[e];
      }
      o4[i] = ov;
    }
    __syncthreads();
  }
}

extern "C" void kernel_launch(void* const* d_in, const int* in_sizes, int n_in,
                              void* d_out, int out_size, void* d_ws, size_t ws_size,
                              hipStream_t stream) {
  const float* x = (const float*)d_in[0];
  const float* gamma = (const float*)d_in[1];
  const float* beta = (const float*)d_in[2];
  const float* w_qkv = (const float*)d_in[3];
  const float* rel = (const float*)d_in[4];
  const float* w_out = (const float*)d_in[5];
  const float* b_out = (const float*)d_in[6];
  float* out = (float*)d_out;

  char* ws = (char*)d_ws;
  size_t off = 0;
  ushort* wqkvB = (ushort*)(ws + off); off += (size_t)12 * 16 * 4096 * 2;
  ushort* woutF = (ushort*)(ws + off); off += (size_t)512 * 512 * 2;
  float* biasP = (float*)(ws + off);   off += (size_t)NHEAD * 64 * 64 * 4;
  ushort* qW = (ushort*)(ws + off);    off += ((size_t)BATCH * 8 * NTOK * 64 + 1024) * 2;
  ushort* kW = (ushort*)(ws + off);    off += ((size_t)BATCH * 8 * NTOK * 64 + 1024) * 2;
  ushort* vW = (ushort*)(ws + off);    off += (size_t)BATCH * 8 * 64 * 64 * 2;
  ushort* xnW = (ushort*)(ws + off);   off += (size_t)BATCH * NTOK * CH * 2;
  ushort* aoW = xnW;  // alias: xn dead after qkv_gemm
  (void)ws_size;

  prep_kernel<<<1024, 256, 0, stream>>>(w_qkv, w_out, rel, wqkvB, woutF, biasP);
  ln_kernel<<<BATCH, 256, 0, stream>>>(x, gamma, beta, xnW);
  qkv_gemm<<<BATCH / 2 * 12, 256, 0, stream>>>(xnW, wqkvB, qW, kW, vW);
  attn2<<<BATCH, 512, 0, stream>>>(qW, kW, vW, biasP, aoW);
  proj_kernel<<<BATCH / 2 * 4, 256, 0, stream>>>(aoW, woutF, b_out, x, out);
}

// Round 7
// 617.911 us; speedup vs baseline: 2.5853x; 1.0367x over previous
//
#include <hip/hip_runtime.h>

#define BATCH 2048
#define CH 512
#define NTOK 49
#define NHEAD 8
#define DHEAD 64

typedef __attribute__((ext_vector_type(8))) short bf16x8;
typedef __attribute__((ext_vector_type(4))) float f32x4;

__device__ __forceinline__ ushort f2bf(float f) {
  union { float f; unsigned u; } v; v.f = f;
  unsigned r = v.u + 0x7fffu + ((v.u >> 16) & 1u);
  return (ushort)(r >> 16);
}

__device__ __forceinline__ float bf2f(ushort u) {
  union { unsigned u; float f; } v; v.u = ((unsigned)u) << 16;
  return v.f;
}

#define MFMA16(a, b, c) __builtin_amdgcn_mfma_f32_16x16x32_bf16((a), (b), (c), 0, 0, 0)

#define GLOAD_LDS16(gsrc, ldst)                                                  \
  __builtin_amdgcn_global_load_lds((const __attribute__((address_space(1))) void*)(gsrc), \
                                   (__attribute__((address_space(3))) void*)(ldst), 16, 0, 0)

// ---------------- Kernel 0: packed weights + padded bias table ----------------
// wqkvB[nb][kk] = 8KB block [cbs(8)][lane(64)][8]: o = nb*128+cbs*16+(lane&15), c = kk*32+(lane>>4)*8+j
// woutF[cb][ks][lane][8]: o = cb*16+(lane&15), c = ks*32+(lane>>4)*8+j
// biasP[h][64][64] f32: (n<49 && m<49) ? swin_bias : -1e30
__global__ void prep_kernel(const float* __restrict__ w_qkv, const float* __restrict__ w_out,
                            const float* __restrict__ rel, ushort* __restrict__ wqkvB,
                            ushort* __restrict__ woutF, float* __restrict__ biasP) {
  int tid = blockIdx.x * blockDim.x + threadIdx.x;
  int stride = gridDim.x * blockDim.x;
  for (int i = tid; i < 12 * 16 * 8 * 64 * 8; i += stride) {
    int j = i & 7, lane = (i >> 3) & 63, cbs = (i >> 9) & 7, kk = (i >> 12) & 15, nb = i >> 16;
    int o = nb * 128 + cbs * 16 + (lane & 15);
    int c = kk * 32 + (lane >> 4) * 8 + j;
    wqkvB[i] = f2bf(w_qkv[c * 1536 + o]);
  }
  for (int i = tid; i < 32 * 16 * 64 * 8; i += stride) {
    int j = i & 7, lane = (i >> 3) & 63, ks = (i >> 9) & 15, cb = i >> 13;
    int o = cb * 16 + (lane & 15);
    int c = ks * 32 + (lane >> 4) * 8 + j;
    woutF[i] = f2bf(w_out[c * 512 + o]);
  }
  for (int i = tid; i < NHEAD * 64 * 64; i += stride) {
    int h = i >> 12, n = (i >> 6) & 63, m = i & 63;
    float v = -1e30f;
    if (n < NTOK && m < NTOK) {
      int dh = n / 7 - m / 7 + 6;
      int dw = n % 7 - m % 7 + 6;
      v = rel[(dh * 13 + dw) * 8 + h];
    }
    biasP[i] = v;
  }
}

// ---------------- Kernel 1: one-pass LayerNorm, x[b][c][n] f32 -> xn bf16 [b][n][c] ----------------
__global__ __launch_bounds__(256) void ln_kernel(const float* __restrict__ x,
                                                 const float* __restrict__ gamma,
                                                 const float* __restrict__ beta,
                                                 ushort* __restrict__ xnW) {
  int b = blockIdx.x;
  int t = threadIdx.x;
  __shared__ ushort xsb[CH][NTOK];
  __shared__ float muL[64], rsL[64];
  const float4* x4 = (const float4*)(x + (size_t)b * CH * NTOK);
  for (int i4 = t; i4 < CH * NTOK / 4; i4 += 256) {
    float4 v = x4[i4];
    int lf = i4 * 4;
#pragma unroll
    for (int e = 0; e < 4; e++) {
      int idx = lf + e;
      int c = idx / NTOK, n = idx - c * NTOK;
      xsb[c][n] = f2bf(((const float*)&v)[e]);
    }
  }
  __syncthreads();
  int row = t >> 2, sub = t & 3;
  float s = 0.f, s2 = 0.f;
  if (row < NTOK) {
    for (int c = sub; c < CH; c += 4) {
      float v = bf2f(xsb[c][row]);
      s += v;
      s2 += v * v;
    }
  }
  s += __shfl_xor(s, 1);
  s += __shfl_xor(s, 2);
  s2 += __shfl_xor(s2, 1);
  s2 += __shfl_xor(s2, 2);
  if (sub == 0 && row < NTOK) {
    float m = s * (1.f / CH);
    muL[row] = m;
    rsL[row] = rsqrtf(s2 * (1.f / CH) - m * m + 1e-5f);
  }
  __syncthreads();
  ushort* dst = xnW + (size_t)b * NTOK * CH;
  for (int i = t; i < NTOK * 64; i += 256) {
    int n = i >> 6, c0 = (i & 63) * 8;
    float mu = muL[n], rs = rsL[n];
    ushort tmp[8];
#pragma unroll
    for (int j = 0; j < 8; j++) {
      int c = c0 + j;
      tmp[j] = f2bf((bf2f(xsb[c][n]) - mu) * rs * gamma[c] + beta[c]);
    }
    *(uint4*)(dst + (size_t)n * CH + c0) = *(const uint4*)tmp;
  }
}

// ---------------- Kernel 2: QKV GEMM, flat-M 128x128 tiles (no pad rows) ----------------
// xn viewed as [100352 x 512]; 784 M-blocks x 12 N-blocks. A via LDS dbuf, B direct from L2.
__global__ __launch_bounds__(256, 4) void qkv_gemm(const ushort* __restrict__ xnW,
                                                   const ushort* __restrict__ wqkvB,
                                                   ushort* __restrict__ qW,
                                                   ushort* __restrict__ kW,
                                                   ushort* __restrict__ vW) {
  int bid = blockIdx.x;
  int f = (bid & 7) * 1176 + (bid >> 3);  // bijective XCD swizzle (9408 = 8*1176)
  int mb = f / 12, nb = f - mb * 12;
  int r0 = mb * 128;
  int t = threadIdx.x, lane = t & 63, w = t >> 6;
  int wm = w >> 1, wn = w & 1;

  // staging: 2 buffers x A[128][32us] (8KB each); epilogue reuses as oL[64][136]
  __shared__ __align__(16) ushort lds[8704];

  const int arow = lane & 15, g = lane >> 4;
  int srow0 = w * 16 + (lane >> 2);
  int cL = lane & 3;
  const ushort* wBbase = wqkvB + (size_t)nb * 16 * 4096;
  const ushort* xbase = xnW + (size_t)r0 * CH;

  // stage step 0 -> buf 0 (all 128 rows real: no guards, no pad-zeroing)
#pragma unroll
  for (int i = 0; i < 2; i++) {
    int row = i * 64 + srow0;
    int cG = cL ^ ((row >> 1) & 3);
    GLOAD_LDS16(xbase + (size_t)row * CH + cG * 8, lds + (i * 64 + w * 16) * 32);
  }
  __syncthreads();

  f32x4 acc[4][4];
#pragma unroll
  for (int mt = 0; mt < 4; mt++)
#pragma unroll
    for (int nt = 0; nt < 4; nt++) acc[mt][nt] = (f32x4){0.f, 0.f, 0.f, 0.f};

  int cur = 0;
  for (int step = 0; step < 16; ++step) {
    // B-frags straight from global (L2-hot, frag-packed, 1KB coalesced per frag)
    const ushort* wp = wBbase + (size_t)step * 4096 + (wn * 4) * 512 + lane * 8;
    bf16x8 bfr[4];
#pragma unroll
    for (int nt = 0; nt < 4; nt++) bfr[nt] = *(const bf16x8*)(wp + nt * 512);
    // prefetch next A tile
    if (step < 15) {
      int nxt = cur ^ 1, kk = step + 1;
#pragma unroll
      for (int i = 0; i < 2; i++) {
        int row = i * 64 + srow0;
        int cG = cL ^ ((row >> 1) & 3);
        GLOAD_LDS16(xbase + (size_t)row * CH + kk * 32 + cG * 8,
                    lds + nxt * 4096 + (i * 64 + w * 16) * 32);
      }
    }
    const ushort* lA = lds + cur * 4096;
    bf16x8 afr[4];
#pragma unroll
    for (int mt = 0; mt < 4; mt++) {
      int row = wm * 64 + mt * 16 + arow;
      afr[mt] = *(const bf16x8*)&lA[row * 32 + (g ^ ((row >> 1) & 3)) * 8];
    }
#pragma unroll
    for (int mt = 0; mt < 4; mt++)
#pragma unroll
      for (int nt = 0; nt < 4; nt++) acc[mt][nt] = MFMA16(afr[mt], bfr[nt], acc[mt][nt]);
    __syncthreads();
    cur ^= 1;
  }

  // epilogue: per row-half (wm half) through LDS; scatter rows to (b = grow/49, n = grow%49)
  ushort(*oL)[136] = (ushort(*)[136])lds;
  int h0 = (nb & 3) * 2;
  int sct = nb >> 2;  // 0=q 1=k 2=v
#pragma unroll
  for (int hh = 0; hh < 2; hh++) {
    if (wm == hh) {
#pragma unroll
      for (int mt = 0; mt < 4; mt++)
#pragma unroll
        for (int nt = 0; nt < 4; nt++)
#pragma unroll
          for (int r = 0; r < 4; r++) {
            int rn = mt * 16 + 4 * g + r;
            oL[rn][wn * 64 + nt * 16 + arow] = f2bf(acc[mt][nt][r]);
          }
    }
    __syncthreads();
    if (sct < 2) {
      ushort* dst = (sct == 0 ? qW : kW);
      for (int i = t; i < 64 * 16; i += 256) {
        int rn = i >> 4, c8 = i & 15;
        int grow = r0 + hh * 64 + rn;
        int b = grow / 49, n = grow - b * 49;
        int h = h0 + (c8 >> 3);
        *(uint4*)(dst + (size_t)(b * 8 + h) * (NTOK * 64) + n * 64 + (c8 & 7) * 8) =
            *(const uint4*)&oL[rn][c8 * 8];
      }
    } else {
      // vT[b][h][d][n], elementwise scatter (rows cross batch boundaries).
      // vT pads (n>=49) never written: attn2's P is exactly 0 there and poison is finite bf16.
      for (int i = t; i < 64 * 128; i += 256) {
        int rn = i & 63, col = i >> 6;  // row-fast for store coalescing
        int grow = r0 + hh * 64 + rn;
        int b = grow / 49, n = grow - b * 49;
        int h = h0 + (col >> 6), d = col & 63;
        vW[(size_t)(b * 8 + h) * 4096 + d * 64 + n] = oL[rn][col];
      }
    }
    __syncthreads();
  }
}

// ---------------- Kernel 3: attention, one head per wave, zero block barriers ----------------
__global__ __launch_bounds__(512, 4) void attn2(const ushort* __restrict__ qW,
                                                const ushort* __restrict__ kW,
                                                const ushort* __restrict__ vW,
                                                const float* __restrict__ biasP,
                                                ushort* __restrict__ aoW) {
  int b = blockIdx.x;
  int t = threadIdx.x;
  int lane = t & 63;
  int h = t >> 6;

  __shared__ ushort pL[8][64][72];
  ushort(*pl)[72] = pL[h];

  const int c = lane & 15, g = lane >> 4;
  const ushort* qb = qW + (size_t)(b * 8 + h) * NTOK * 64;
  const ushort* kb = kW + (size_t)(b * 8 + h) * NTOK * 64;
  const ushort* vb = vW + (size_t)(b * 8 + h) * 64 * 64;
  const float* bp = biasP + h * 64 * 64;

  f32x4 s[4][4];
#pragma unroll
  for (int mt = 0; mt < 4; mt++)
#pragma unroll
    for (int nt = 0; nt < 4; nt++) s[mt][nt] = (f32x4){0.f, 0.f, 0.f, 0.f};
#pragma unroll
  for (int ks = 0; ks < 2; ks++) {
    bf16x8 kf[4];
#pragma unroll
    for (int nt = 0; nt < 4; nt++)
      kf[nt] = *(const bf16x8*)(kb + (size_t)(nt * 16 + c) * 64 + ks * 32 + g * 8);
#pragma unroll
    for (int mt = 0; mt < 4; mt++) {
      bf16x8 qf = *(const bf16x8*)(qb + (size_t)(mt * 16 + c) * 64 + ks * 32 + g * 8);
#pragma unroll
      for (int nt = 0; nt < 4; nt++) s[mt][nt] = MFMA16(qf, kf[nt], s[mt][nt]);
    }
  }
#pragma unroll
  for (int mt = 0; mt < 4; mt++)
#pragma unroll
    for (int nt = 0; nt < 4; nt++)
#pragma unroll
      for (int r = 0; r < 4; r++) {
        int n = mt * 16 + 4 * g + r;
        int m = nt * 16 + c;
        s[mt][nt][r] = s[mt][nt][r] * 0.125f + bp[n * 64 + m];
      }

#pragma unroll
  for (int mt = 0; mt < 4; mt++)
#pragma unroll
    for (int r = 0; r < 4; r++) {
      float mx = fmaxf(fmaxf(s[mt][0][r], s[mt][1][r]), fmaxf(s[mt][2][r], s[mt][3][r]));
      mx = fmaxf(mx, __shfl_xor(mx, 1));
      mx = fmaxf(mx, __shfl_xor(mx, 2));
      mx = fmaxf(mx, __shfl_xor(mx, 4));
      mx = fmaxf(mx, __shfl_xor(mx, 8));
      float p0 = __expf(s[mt][0][r] - mx);
      float p1 = __expf(s[mt][1][r] - mx);
      float p2 = __expf(s[mt][2][r] - mx);
      float p3 = __expf(s[mt][3][r] - mx);
      float sum = p0 + p1 + p2 + p3;
      sum += __shfl_xor(sum, 1);
      sum += __shfl_xor(sum, 2);
      sum += __shfl_xor(sum, 4);
      sum += __shfl_xor(sum, 8);
      float rinv = 1.f / sum;
      int n = mt * 16 + 4 * g + r;
      pl[n][0 * 16 + c] = f2bf(p0 * rinv);
      pl[n][1 * 16 + c] = f2bf(p1 * rinv);
      pl[n][2 * 16 + c] = f2bf(p2 * rinv);
      pl[n][3 * 16 + c] = f2bf(p3 * rinv);
    }

  f32x4 o[4][4];
#pragma unroll
  for (int mt = 0; mt < 4; mt++)
#pragma unroll
    for (int nt = 0; nt < 4; nt++) o[mt][nt] = (f32x4){0.f, 0.f, 0.f, 0.f};
#pragma unroll
  for (int ks = 0; ks < 2; ks++) {
    bf16x8 vf[4];
#pragma unroll
    for (int nt = 0; nt < 4; nt++)
      vf[nt] = *(const bf16x8*)(vb + (size_t)(nt * 16 + c) * 64 + ks * 32 + g * 8);
#pragma unroll
    for (int mt = 0; mt < 4; mt++) {
      bf16x8 pf = *(const bf16x8*)&pl[mt * 16 + c][ks * 32 + g * 8];
#pragma unroll
      for (int nt = 0; nt < 4; nt++) o[mt][nt] = MFMA16(pf, vf[nt], o[mt][nt]);
    }
  }

#pragma unroll
  for (int mt = 0; mt < 4; mt++)
#pragma unroll
    for (int nt = 0; nt < 4; nt++)
#pragma unroll
      for (int r = 0; r < 4; r++) {
        int n = mt * 16 + 4 * g + r;
        pl[n][nt * 16 + c] = f2bf(o[mt][nt][r]);
      }
  ushort* ao = aoW + (size_t)b * NTOK * CH + h * 64;
  for (int i = lane; i < NTOK * 8; i += 64) {
    int row = i >> 3, c8 = i & 7;
    *(uint4*)(ao + (size_t)row * CH + c8 * 8) = *(const uint4*)&pl[row][c8 * 8];
  }
}

// ---------------- Kernel 4: out-proj GEMM; A via LDS dbuf, B direct from L2 ----------------
__global__ __launch_bounds__(256, 4) void proj_kernel(const ushort* __restrict__ aoW,
                                                      const ushort* __restrict__ woutF,
                                                      const float* __restrict__ b_out,
                                                      const float* __restrict__ x,
                                                      float* __restrict__ out) {
  int bid = blockIdx.x;
  int f = (bid & 7) * 512 + (bid >> 3);  // bijective (4096 = 8*512)
  int mb = f >> 2, nbp = f & 3;
  int b0 = mb * 2;
  int t = threadIdx.x, lane = t & 63, w = t >> 6;
  int wm = w >> 1, wn = w & 1;

  __shared__ __align__(16) char ldsraw[33792];  // staging 16KB; epilogue f32 [64][132]
  ushort* lds = (ushort*)ldsraw;
  float(*oL)[132] = (float(*)[132])ldsraw;

  for (int i = t; i < 2 * 30 * 32; i += 256) {
    int buf = i >= 960;
    int r2 = i - buf * 960;
    int rr = r2 >> 5;
    int row = (rr < 15) ? (49 + rr) : (98 + rr);
    lds[buf * 4096 + row * 32 + (i & 31)] = 0;
  }

  const int arow = lane & 15, g = lane >> 4;
  int srow0 = w * 16 + (lane >> 2);
  int cL = lane & 3;

  {
#pragma unroll
    for (int i = 0; i < 2; i++) {
      int row = i * 64 + srow0;
      int n = row & 63, bb = b0 + (row >> 6);
      int cG = cL ^ ((row >> 1) & 3);
      if (n < NTOK)
        GLOAD_LDS16(aoW + ((size_t)bb * NTOK + n) * CH + cG * 8, lds + (i * 64 + w * 16) * 32);
    }
  }
  __syncthreads();

  f32x4 acc[4][4];
#pragma unroll
  for (int mt = 0; mt < 4; mt++)
#pragma unroll
    for (int nt = 0; nt < 4; nt++) acc[mt][nt] = (f32x4){0.f, 0.f, 0.f, 0.f};

  int cur = 0;
  for (int step = 0; step < 16; ++step) {
    const ushort* wp = woutF + ((size_t)(nbp * 8 + wn * 4) * 16 + step) * 512 + lane * 8;
    bf16x8 bfr[4];
#pragma unroll
    for (int nt = 0; nt < 4; nt++) bfr[nt] = *(const bf16x8*)(wp + (size_t)nt * 16 * 512);
    if (step < 15) {
      int nxt = cur ^ 1, kk = step + 1;
#pragma unroll
      for (int i = 0; i < 2; i++) {
        int row = i * 64 + srow0;
        int n = row & 63, bb = b0 + (row >> 6);
        int cG = cL ^ ((row >> 1) & 3);
        if (n < NTOK)
          GLOAD_LDS16(aoW + ((size_t)bb * NTOK + n) * CH + kk * 32 + cG * 8,
                      lds + nxt * 4096 + (i * 64 + w * 16) * 32);
      }
    }
    const ushort* lA = lds + cur * 4096;
    bf16x8 afr[4];
#pragma unroll
    for (int mt = 0; mt < 4; mt++) {
      int row = wm * 64 + mt * 16 + arow;
      afr[mt] = *(const bf16x8*)&lA[row * 32 + (g ^ ((row >> 1) & 3)) * 8];
    }
#pragma unroll
    for (int mt = 0; mt < 4; mt++)
#pragma unroll
      for (int nt = 0; nt < 4; nt++) acc[mt][nt] = MFMA16(afr[mt], bfr[nt], acc[mt][nt]);
    __syncthreads();
    cur ^= 1;
  }

  const float* bo = b_out + nbp * 128;
#pragma unroll
  for (int hh = 0; hh < 2; hh++) {
    if (wm == hh) {
#pragma unroll
      for (int mt = 0; mt < 4; mt++)
#pragma unroll
        for (int nt = 0; nt < 4; nt++)
#pragma unroll
          for (int r = 0; r < 4; r++) {
            int rn = mt * 16 + 4 * g + r;
            if (rn < NTOK) oL[rn][wn * 64 + nt * 16 + arow] = acc[mt][nt][r];
          }
    }
    __syncthreads();
    int b = b0 + hh;
    const float4* x4 = (const float4*)(x + ((size_t)b * CH + nbp * 128) * NTOK);
    float4* o4 = (float4*)(out + ((size_t)b * CH + nbp * 128) * NTOK);
    for (int i = t; i < 1568; i += 256) {
      float4 xv = x4[i];
      float4 ov;
      int lf = i * 4;
#pragma unroll
      for (int e = 0; e < 4; e++) {
        int cl = (lf + e) / NTOK, n = (lf + e) - cl * NTOK;
        ((float*)&ov)[e] = oL[n][cl] + bo[cl] + ((const float*)&xv)[e];
      }
      o4[i] = ov;
    }
    __syncthreads();
  }
}

extern "C" void kernel_launch(void* const* d_in, const int* in_sizes, int n_in,
                              void* d_out, int out_size, void* d_ws, size_t ws_size,
                              hipStream_t stream) {
  const float* x = (const float*)d_in[0];
  const float* gamma = (const float*)d_in[1];
  const float* beta = (const float*)d_in[2];
  const float* w_qkv = (const float*)d_in[3];
  const float* rel = (const float*)d_in[4];
  const float* w_out = (const float*)d_in[5];
  const float* b_out = (const float*)d_in[6];
  float* out = (float*)d_out;

  char* ws = (char*)d_ws;
  size_t off = 0;
  ushort* wqkvB = (ushort*)(ws + off); off += (size_t)12 * 16 * 4096 * 2;
  ushort* woutF = (ushort*)(ws + off); off += (size_t)512 * 512 * 2;
  float* biasP = (float*)(ws + off);   off += (size_t)NHEAD * 64 * 64 * 4;
  ushort* qW = (ushort*)(ws + off);    off += ((size_t)BATCH * 8 * NTOK * 64 + 1024) * 2;
  ushort* kW = (ushort*)(ws + off);    off += ((size_t)BATCH * 8 * NTOK * 64 + 1024) * 2;
  ushort* vW = (ushort*)(ws + off);    off += (size_t)BATCH * 8 * 64 * 64 * 2;
  ushort* xnW = (ushort*)(ws + off);   off += (size_t)BATCH * NTOK * CH * 2;
  ushort* aoW = xnW;  // alias: xn dead after qkv_gemm
  (void)ws_size;

  prep_kernel<<<1024, 256, 0, stream>>>(w_qkv, w_out, rel, wqkvB, woutF, biasP);
  ln_kernel<<<BATCH, 256, 0, stream>>>(x, gamma, beta, xnW);
  qkv_gemm<<<784 * 12, 256, 0, stream>>>(xnW, wqkvB, qW, kW, vW);
  attn2<<<BATCH, 512, 0, stream>>>(qW, kW, vW, biasP, aoW);
  proj_kernel<<<BATCH / 2 * 4, 256, 0, stream>>>(aoW, woutF, b_out, x, out);
}

// Round 9
// 589.152 us; speedup vs baseline: 2.7115x; 1.0488x over previous
//
#include <hip/hip_runtime.h>

#define BATCH 2048
#define CH 512
#define NTOK 49
#define NHEAD 8
#define DHEAD 64

typedef __attribute__((ext_vector_type(8))) short bf16x8;
typedef __attribute__((ext_vector_type(4))) float f32x4;

__device__ __forceinline__ ushort f2bf(float f) {
  union { float f; unsigned u; } v; v.f = f;
  unsigned r = v.u + 0x7fffu + ((v.u >> 16) & 1u);
  return (ushort)(r >> 16);
}

__device__ __forceinline__ float bf2f(ushort u) {
  union { unsigned u; float f; } v; v.u = ((unsigned)u) << 16;
  return v.f;
}

#define MFMA16(a, b, c) __builtin_amdgcn_mfma_f32_16x16x32_bf16((a), (b), (c), 0, 0, 0)

#define GLOAD_LDS16(gsrc, ldst)                                                  \
  __builtin_amdgcn_global_load_lds((const __attribute__((address_space(1))) void*)(gsrc), \
                                   (__attribute__((address_space(3))) void*)(ldst), 16, 0, 0)

// ---------------- Kernel 0: packed weights + padded bias table ----------------
__global__ void prep_kernel(const float* __restrict__ w_qkv, const float* __restrict__ w_out,
                            const float* __restrict__ rel, ushort* __restrict__ wqkvB,
                            ushort* __restrict__ woutF, float* __restrict__ biasP) {
  int tid = blockIdx.x * blockDim.x + threadIdx.x;
  int stride = gridDim.x * blockDim.x;
  for (int i = tid; i < 12 * 16 * 8 * 64 * 8; i += stride) {
    int j = i & 7, lane = (i >> 3) & 63, cbs = (i >> 9) & 7, kk = (i >> 12) & 15, nb = i >> 16;
    int o = nb * 128 + cbs * 16 + (lane & 15);
    int c = kk * 32 + (lane >> 4) * 8 + j;
    wqkvB[i] = f2bf(w_qkv[c * 1536 + o]);
  }
  for (int i = tid; i < 32 * 16 * 64 * 8; i += stride) {
    int j = i & 7, lane = (i >> 3) & 63, ks = (i >> 9) & 15, cb = i >> 13;
    int o = cb * 16 + (lane & 15);
    int c = ks * 32 + (lane >> 4) * 8 + j;
    woutF[i] = f2bf(w_out[c * 512 + o]);
  }
  for (int i = tid; i < NHEAD * 64 * 64; i += stride) {
    int h = i >> 12, n = (i >> 6) & 63, m = i & 63;
    float v = -1e30f;
    if (n < NTOK && m < NTOK) {
      int dh = n / 7 - m / 7 + 6;
      int dw = n % 7 - m % 7 + 6;
      v = rel[(dh * 13 + dw) * 8 + h];
    }
    biasP[i] = v;
  }
}

// ---------------- Kernel 1: one-pass LayerNorm, x[b][c][n] f32 -> xn bf16 [b][n][c] ----------------
__global__ __launch_bounds__(256) void ln_kernel(const float* __restrict__ x,
                                                 const float* __restrict__ gamma,
                                                 const float* __restrict__ beta,
                                                 ushort* __restrict__ xnW) {
  int b = blockIdx.x;
  int t = threadIdx.x;
  __shared__ ushort xsb[CH][NTOK];
  __shared__ float muL[64], rsL[64];
  const float4* x4 = (const float4*)(x + (size_t)b * CH * NTOK);
  for (int i4 = t; i4 < CH * NTOK / 4; i4 += 256) {
    float4 v = x4[i4];
    int lf = i4 * 4;
#pragma unroll
    for (int e = 0; e < 4; e++) {
      int idx = lf + e;
      int c = idx / NTOK, n = idx - c * NTOK;
      xsb[c][n] = f2bf(((const float*)&v)[e]);
    }
  }
  __syncthreads();
  int row = t >> 2, sub = t & 3;
  float s = 0.f, s2 = 0.f;
  if (row < NTOK) {
    for (int c = sub; c < CH; c += 4) {
      float v = bf2f(xsb[c][row]);
      s += v;
      s2 += v * v;
    }
  }
  s += __shfl_xor(s, 1);
  s += __shfl_xor(s, 2);
  s2 += __shfl_xor(s2, 1);
  s2 += __shfl_xor(s2, 2);
  if (sub == 0 && row < NTOK) {
    float m = s * (1.f / CH);
    muL[row] = m;
    rsL[row] = rsqrtf(s2 * (1.f / CH) - m * m + 1e-5f);
  }
  __syncthreads();
  ushort* dst = xnW + (size_t)b * NTOK * CH;
  for (int i = t; i < NTOK * 64; i += 256) {
    int n = i >> 6, c0 = (i & 63) * 8;
    float mu = muL[n], rs = rsL[n];
    ushort tmp[8];
#pragma unroll
    for (int j = 0; j < 8; j++) {
      int c = c0 + j;
      tmp[j] = f2bf((bf2f(xsb[c][n]) - mu) * rs * gamma[c] + beta[c]);
    }
    *(uint4*)(dst + (size_t)n * CH + c0) = *(const uint4*)tmp;
  }
}

// ---------------- Kernel 2: QKV GEMM, flat-M 128x128 tiles, BK=64 (8 barriers) ----------------
__global__ __launch_bounds__(256, 4) void qkv_gemm(const ushort* __restrict__ xnW,
                                                   const ushort* __restrict__ wqkvB,
                                                   ushort* __restrict__ qW,
                                                   ushort* __restrict__ kW,
                                                   ushort* __restrict__ vW) {
  int bid = blockIdx.x;
  int f = (bid & 7) * 1176 + (bid >> 3);  // bijective XCD swizzle (9408 = 8*1176)
  int mb = f / 12, nb = f - mb * 12;
  int r0 = mb * 128;
  int t = threadIdx.x, lane = t & 63, w = t >> 6;
  int wm = w >> 1, wn = w & 1;

  // 2 buffers x A[128][64us] = 32KB; epilogue reuses as oL[64][136]
  __shared__ __align__(16) ushort lds[16384];

  const int arow = lane & 15, g = lane >> 4;
  const ushort* wBbase = wqkvB + (size_t)nb * 16 * 4096;
  const ushort* xbase = xnW + (size_t)r0 * CH;

  // staging: thread t, load i: row = (t>>3)+i*32, phys slot = t&7,
  // global chunk = slot ^ (row&7)  (XOR involution; LDS dest stays linear = base + t*16B)
  int drow = t >> 3;
  int slot = t & 7;
  int gchunk = slot ^ (drow & 7);

#pragma unroll
  for (int i = 0; i < 4; i++) {
    int row = drow + i * 32;
    GLOAD_LDS16(xbase + (size_t)row * CH + gchunk * 8, lds + i * 2048 + t * 8);
  }
  __syncthreads();

  f32x4 acc[4][4];
#pragma unroll
  for (int mt = 0; mt < 4; mt++)
#pragma unroll
    for (int nt = 0; nt < 4; nt++) acc[mt][nt] = (f32x4){0.f, 0.f, 0.f, 0.f};

  int cur = 0;
  for (int stage = 0; stage < 8; ++stage) {
    if (stage < 7) {
      int nxt = cur ^ 1, kk = stage + 1;
#pragma unroll
      for (int i = 0; i < 4; i++) {
        GLOAD_LDS16(xbase + (size_t)(drow + i * 32) * CH + kk * 64 + gchunk * 8,
                    lds + nxt * 8192 + i * 2048 + t * 8);
      }
    }
    const ushort* lA = lds + cur * 8192;
#pragma unroll
    for (int ks = 0; ks < 2; ks++) {
      int kk2 = stage * 2 + ks;
      const ushort* wp = wBbase + (size_t)kk2 * 4096 + (wn * 4) * 512 + lane * 8;
      bf16x8 bfr[4];
#pragma unroll
      for (int nt = 0; nt < 4; nt++) bfr[nt] = *(const bf16x8*)(wp + nt * 512);
      bf16x8 afr[4];
#pragma unroll
      for (int mt = 0; mt < 4; mt++) {
        int row = wm * 64 + mt * 16 + arow;
        afr[mt] = *(const bf16x8*)&lA[row * 64 + ((ks * 4 + g) ^ (arow & 7)) * 8];
      }
#pragma unroll
      for (int mt = 0; mt < 4; mt++)
#pragma unroll
        for (int nt = 0; nt < 4; nt++) acc[mt][nt] = MFMA16(afr[mt], bfr[nt], acc[mt][nt]);
    }
    __syncthreads();
    cur ^= 1;
  }

  // epilogue: per row-half through LDS; scatter rows to (b = grow/49, n = grow%49)
  ushort(*oL)[136] = (ushort(*)[136])lds;
  int h0 = (nb & 3) * 2;
  int sct = nb >> 2;  // 0=q 1=k 2=v
#pragma unroll
  for (int hh = 0; hh < 2; hh++) {
    if (wm == hh) {
#pragma unroll
      for (int mt = 0; mt < 4; mt++)
#pragma unroll
        for (int nt = 0; nt < 4; nt++)
#pragma unroll
          for (int r = 0; r < 4; r++) {
            int rn = mt * 16 + 4 * g + r;
            oL[rn][wn * 64 + nt * 16 + arow] = f2bf(acc[mt][nt][r]);
          }
    }
    __syncthreads();
    if (sct < 2) {
      ushort* dst = (sct == 0 ? qW : kW);
      for (int i = t; i < 64 * 16; i += 256) {
        int rn = i >> 4, c8 = i & 15;
        int grow = r0 + hh * 64 + rn;
        int b = grow / 49, n = grow - b * 49;
        int h = h0 + (c8 >> 3);
        *(uint4*)(dst + (size_t)(b * 8 + h) * (NTOK * 64) + n * 64 + (c8 & 7) * 8) =
            *(const uint4*)&oL[rn][c8 * 8];
      }
    } else {
      for (int i = t; i < 64 * 128; i += 256) {
        int rn = i & 63, col = i >> 6;
        int grow = r0 + hh * 64 + rn;
        int b = grow / 49, n = grow - b * 49;
        int h = h0 + (col >> 6), d = col & 63;
        vW[(size_t)(b * 8 + h) * 4096 + d * 64 + n] = oL[rn][col];
      }
    }
    __syncthreads();
  }
}

// ---------------- Kernel 3: fused attention + out-proj + bias + residual ----------------
// 512 thr / 8 waves; wave = one head for attn, then 64 proj output cols.
__global__ __launch_bounds__(512) void attnproj(const ushort* __restrict__ qW,
                                                const ushort* __restrict__ kW,
                                                const ushort* __restrict__ vW,
                                                const float* __restrict__ biasP,
                                                const ushort* __restrict__ woutF,
                                                const float* __restrict__ b_out,
                                                const float* __restrict__ x,
                                                float* __restrict__ out) {
  int b = blockIdx.x;
  int t = threadIdx.x;
  int lane = t & 63;
  int w = t >> 6;

  // region reuse: phase1 P per-wave [64][72] (73.7KB) -> aoL bf16 [64][520] -> oL f32 [64][260]
  __shared__ __align__(16) ushort lds[36864];
  ushort(*pl)[72] = (ushort(*)[72])(lds + w * 4608);

  const int c = lane & 15, g = lane >> 4;
  const ushort* qb = qW + (size_t)(b * 8 + w) * NTOK * 64;
  const ushort* kb = kW + (size_t)(b * 8 + w) * NTOK * 64;
  const ushort* vb = vW + (size_t)(b * 8 + w) * 64 * 64;
  const float* bp = biasP + w * 64 * 64;

  // ---- S = Q K^T ----
  f32x4 s[4][4];
#pragma unroll
  for (int mt = 0; mt < 4; mt++)
#pragma unroll
    for (int nt = 0; nt < 4; nt++) s[mt][nt] = (f32x4){0.f, 0.f, 0.f, 0.f};
#pragma unroll
  for (int ks = 0; ks < 2; ks++) {
    bf16x8 kf[4];
#pragma unroll
    for (int nt = 0; nt < 4; nt++)
      kf[nt] = *(const bf16x8*)(kb + (size_t)(nt * 16 + c) * 64 + ks * 32 + g * 8);
#pragma unroll
    for (int mt = 0; mt < 4; mt++) {
      bf16x8 qf = *(const bf16x8*)(qb + (size_t)(mt * 16 + c) * 64 + ks * 32 + g * 8);
#pragma unroll
      for (int nt = 0; nt < 4; nt++) s[mt][nt] = MFMA16(qf, kf[nt], s[mt][nt]);
    }
  }
#pragma unroll
  for (int mt = 0; mt < 4; mt++)
#pragma unroll
    for (int nt = 0; nt < 4; nt++)
#pragma unroll
      for (int r = 0; r < 4; r++) {
        int n = mt * 16 + 4 * g + r;
        int m = nt * 16 + c;
        s[mt][nt][r] = s[mt][nt][r] * 0.125f + bp[n * 64 + m];
      }

  // ---- softmax (in registers, width-16 shuffles) -> P to per-wave LDS ----
#pragma unroll
  for (int mt = 0; mt < 4; mt++)
#pragma unroll
    for (int r = 0; r < 4; r++) {
      float mx = fmaxf(fmaxf(s[mt][0][r], s[mt][1][r]), fmaxf(s[mt][2][r], s[mt][3][r]));
      mx = fmaxf(mx, __shfl_xor(mx, 1));
      mx = fmaxf(mx, __shfl_xor(mx, 2));
      mx = fmaxf(mx, __shfl_xor(mx, 4));
      mx = fmaxf(mx, __shfl_xor(mx, 8));
      float p0 = __expf(s[mt][0][r] - mx);
      float p1 = __expf(s[mt][1][r] - mx);
      float p2 = __expf(s[mt][2][r] - mx);
      float p3 = __expf(s[mt][3][r] - mx);
      float sum = p0 + p1 + p2 + p3;
      sum += __shfl_xor(sum, 1);
      sum += __shfl_xor(sum, 2);
      sum += __shfl_xor(sum, 4);
      sum += __shfl_xor(sum, 8);
      float rinv = 1.f / sum;
      int n = mt * 16 + 4 * g + r;
      pl[n][0 * 16 + c] = f2bf(p0 * rinv);
      pl[n][1 * 16 + c] = f2bf(p1 * rinv);
      pl[n][2 * 16 + c] = f2bf(p2 * rinv);
      pl[n][3 * 16 + c] = f2bf(p3 * rinv);
    }

  // ---- O = P V ----
  f32x4 o[4][4];
#pragma unroll
  for (int mt = 0; mt < 4; mt++)
#pragma unroll
    for (int nt = 0; nt < 4; nt++) o[mt][nt] = (f32x4){0.f, 0.f, 0.f, 0.f};
#pragma unroll
  for (int ks = 0; ks < 2; ks++) {
    bf16x8 vf[4];
#pragma unroll
    for (int nt = 0; nt < 4; nt++)
      vf[nt] = *(const bf16x8*)(vb + (size_t)(nt * 16 + c) * 64 + ks * 32 + g * 8);
#pragma unroll
    for (int mt = 0; mt < 4; mt++) {
      bf16x8 pf = *(const bf16x8*)&pl[mt * 16 + c][ks * 32 + g * 8];
#pragma unroll
      for (int nt = 0; nt < 4; nt++) o[mt][nt] = MFMA16(pf, vf[nt], o[mt][nt]);
    }
  }
  __syncthreads();  // all P reads done; region becomes aoL

  // ---- O -> aoL[64][520] bf16 (pads zeroed) ----
  ushort(*aoL)[520] = (ushort(*)[520])lds;
#pragma unroll
  for (int mt = 0; mt < 4; mt++)
#pragma unroll
    for (int nt = 0; nt < 4; nt++)
#pragma unroll
      for (int r = 0; r < 4; r++) {
        int n = mt * 16 + 4 * g + r;
        aoL[n][w * 64 + nt * 16 + c] = (n < NTOK) ? f2bf(o[mt][nt][r]) : (ushort)0;
      }
  __syncthreads();

  // ---- proj GEMM: [64 x 512] @ [512 x 64] per wave; A from aoL, B from L2 ----
  f32x4 pacc[4][4];
#pragma unroll
  for (int mt = 0; mt < 4; mt++)
#pragma unroll
    for (int nt = 0; nt < 4; nt++) pacc[mt][nt] = (f32x4){0.f, 0.f, 0.f, 0.f};
#pragma unroll 4
  for (int step = 0; step < 16; step++) {
    bf16x8 bfr[4];
#pragma unroll
    for (int nt = 0; nt < 4; nt++)
      bfr[nt] = *(const bf16x8*)(woutF + ((size_t)((w * 4 + nt) * 16 + step)) * 512 + lane * 8);
    bf16x8 afr[4];
#pragma unroll
    for (int mt = 0; mt < 4; mt++)
      afr[mt] = *(const bf16x8*)&aoL[mt * 16 + c][step * 32 + g * 8];
#pragma unroll
    for (int mt = 0; mt < 4; mt++)
#pragma unroll
      for (int nt = 0; nt < 4; nt++) pacc[mt][nt] = MFMA16(afr[mt], bfr[nt], pacc[mt][nt]);
  }

  // ---- epilogue: two 256-col chunks; transpose via oL f32 [64][260], +bias +residual ----
  float(*oL)[260] = (float(*)[260])lds;
  for (int half = 0; half < 2; half++) {
    __syncthreads();  // aoL reads done (half 0) / previous stores done (half 1)
    if ((w >> 2) == half) {
      int wl = w & 3;
#pragma unroll
      for (int mt = 0; mt < 4; mt++)
#pragma unroll
        for (int nt = 0; nt < 4; nt++)
#pragma unroll
          for (int r = 0; r < 4; r++) {
            int rn = mt * 16 + 4 * g + r;
            if (rn < NTOK) oL[rn][wl * 64 + nt * 16 + c] = pacc[mt][nt][r];
          }
    }
    __syncthreads();
    int c0 = half * 256;
    const float4* x4 = (const float4*)(x + ((size_t)b * CH + c0) * NTOK);
    float4* o4 = (float4*)(out + ((size_t)b * CH + c0) * NTOK);
    const float* bo = b_out + c0;
    for (int i = t; i < 3136; i += 512) {
      float4 xv = x4[i];
      float4 ov;
      int lf = i * 4;
#pragma unroll
      for (int e = 0; e < 4; e++) {
        int cl = (lf + e) / NTOK, n = (lf + e) - cl * NTOK;
        ((float*)&ov)[e] = oL[n][cl] + bo[cl] + ((const float*)&xv)[e];
      }
      o4[i] = ov;
    }
  }
}

extern "C" void kernel_launch(void* const* d_in, const int* in_sizes, int n_in,
                              void* d_out, int out_size, void* d_ws, size_t ws_size,
                              hipStream_t stream) {
  const float* x = (const float*)d_in[0];
  const float* gamma = (const float*)d_in[1];
  const float* beta = (const float*)d_in[2];
  const float* w_qkv = (const float*)d_in[3];
  const float* rel = (const float*)d_in[4];
  const float* w_out = (const float*)d_in[5];
  const float* b_out = (const float*)d_in[6];
  float* out = (float*)d_out;

  char* ws = (char*)d_ws;
  size_t off = 0;
  ushort* wqkvB = (ushort*)(ws + off); off += (size_t)12 * 16 * 4096 * 2;
  ushort* woutF = (ushort*)(ws + off); off += (size_t)512 * 512 * 2;
  float* biasP = (float*)(ws + off);   off += (size_t)NHEAD * 64 * 64 * 4;
  ushort* qW = (ushort*)(ws + off);    off += ((size_t)BATCH * 8 * NTOK * 64 + 1024) * 2;
  ushort* kW = (ushort*)(ws + off);    off += ((size_t)BATCH * 8 * NTOK * 64 + 1024) * 2;
  ushort* vW = (ushort*)(ws + off);    off += (size_t)BATCH * 8 * 64 * 64 * 2;
  ushort* xnW = (ushort*)(ws + off);   off += (size_t)BATCH * NTOK * CH * 2;
  (void)ws_size;

  prep_kernel<<<1024, 256, 0, stream>>>(w_qkv, w_out, rel, wqkvB, woutF, biasP);
  ln_kernel<<<BATCH, 256, 0, stream>>>(x, gamma, beta, xnW);
  qkv_gemm<<<784 * 12, 256, 0, stream>>>(xnW, wqkvB, qW, kW, vW);
  attnproj<<<BATCH, 512, 0, stream>>>(qW, kW, vW, biasP, woutF, b_out, x, out);
}